// Round 4
// baseline (1125.953 us; speedup 1.0000x reference)
//
#include <hip/hip_runtime.h>

// SigLIP contrastive loss:
//   logits = emb1 @ emb2^T / 0.07           [B,B], B=8192, D=1024
//   loss = ( sum_i softplus(-l_ii) + sum_{i!=j} softplus(l_ij) ) / B
// R3: 256x256 8-phase MX-fp8 GEMM (T2 swizzle + T3/T4 counted vmcnt + T5
// setprio), softplus+reduce epilogue fused. 8 waves, 128KiB LDS dbuf.

#define B_DIM 8192
#define K_DIM 1024
#define BM 256
#define BKB 128                // K bytes per K-tile (fp8 elems)
#define NT (K_DIM / BKB)       // 8 K-tiles

typedef int i32x4 __attribute__((ext_vector_type(4)));
typedef int i32x8 __attribute__((ext_vector_type(8)));
typedef float f32x4 __attribute__((ext_vector_type(4)));

// f32 -> OCP e4m3 (hardware cvt, saturating), 8 elems/thread/iter.
__global__ void cvt_fp8_kernel(const float* __restrict__ in,
                               unsigned int* __restrict__ out, int n8,
                               float scale) {
  int i = blockIdx.x * blockDim.x + threadIdx.x;
  int stride = gridDim.x * blockDim.x;
  const float4* in4 = (const float4*)in;
  uint2* out2 = (uint2*)out;
  for (; i < n8; i += stride) {
    float4 v0 = in4[2 * i];
    float4 v1 = in4[2 * i + 1];
    unsigned int w0 = 0, w1 = 0;
    w0 = __builtin_amdgcn_cvt_pk_fp8_f32(v0.x * scale, v0.y * scale, w0, 0);
    w0 = __builtin_amdgcn_cvt_pk_fp8_f32(v0.z * scale, v0.w * scale, w0, 1);
    w1 = __builtin_amdgcn_cvt_pk_fp8_f32(v1.x * scale, v1.y * scale, w1, 0);
    w1 = __builtin_amdgcn_cvt_pk_fp8_f32(v1.z * scale, v1.w * scale, w1, 1);
    out2[i] = make_uint2(w0, w1);
  }
}

// Cheap softplus accumulate: softplus(x) = max(x,0) + log(1+exp(-|x|)).
template <bool DIAG>
__device__ __forceinline__ float softplus_sum(const f32x4 (&acc)[8][4],
                                              int rbase, int cbase) {
  float lin = 0.f, cor = 0.f;
#pragma unroll
  for (int m = 0; m < 8; ++m) {
#pragma unroll
    for (int n = 0; n < 4; ++n) {
#pragma unroll
      for (int r = 0; r < 4; ++r) {
        float x = acc[m][n][r];
        if (DIAG) {
          int row = rbase + m * 16 + r;
          int col = cbase + n * 16;
          if (row == col) x = -x;  // diagonal: softplus(-l_ii)
        }
        lin += fmaxf(x, 0.f);
        cor += __logf(1.f + __expf(-fabsf(x)));
      }
    }
  }
  return lin + cor;
}

// Stage one half-tile slice j: 512 threads x 16B, pre-swizzled global source
// (chunk16 ^= row&7) so linear global_load_lds lands the swizzled layout.
#define STAGE(BUF, HALF, J, K0, ISA)                                          \
  __builtin_amdgcn_global_load_lds(                                           \
      (const __attribute__((address_space(1))) void*)(const void*)(           \
          ((ISA) ? Aga : Bga) +                                               \
          (size_t)((HALF) * 128 + (J) * 64 + s_row) * K_DIM + (K0) + s_c),    \
      (__attribute__((address_space(3))) void*)(void*)(lds + (BUF) * 65536 +  \
          ((ISA) ? 0 : 32768) + (HALF) * 16384 + (J) * 8192 + wave * 1024),   \
      16, 0, 0)

// Load one 16x16x128 fp8 fragment (32B/lane) from swizzled LDS.
#define LDFRAG(OUT, BASEOFF, ROW)                                             \
  {                                                                           \
    const unsigned char* _b = lds + (BASEOFF) + (unsigned)(ROW) * 128;        \
    i32x4 _lo = *(const i32x4*)(_b + ((kch * 32) ^ sw));                      \
    i32x4 _hi = *(const i32x4*)(_b + ((kch * 32 + 16) ^ sw));                 \
    OUT = __builtin_shufflevector(_lo, _hi, 0, 1, 2, 3, 4, 5, 6, 7);          \
  }

// Group-specific counted vmcnt gating tile T+1 (issue order A0,B0 | B1,A1):
// (wr0,wch0) needs A0,B0 -> vmcnt(4); (wr0,wch1) A0,B1 -> vmcnt(2);
// wr1 needs A1 (last) -> vmcnt(0). Sits before a barrier so all waves' slices
// are resident before any wave reads (vmcnt is per-wave).
#define VMWAIT()                                                              \
  if (wr == 0) {                                                              \
    if (wch == 0) asm volatile("s_waitcnt vmcnt(4)" ::: "memory");            \
    else          asm volatile("s_waitcnt vmcnt(2)" ::: "memory");            \
  } else          asm volatile("s_waitcnt vmcnt(0)" ::: "memory")

// One phase: quadrant (MH,NH). ds_reads -> [PRE] -> [STG] -> barrier ->
// lgkm(0) -> 8 MFMA (setprio-wrapped) -> barrier.
#define PHASE(MH, NH, PRE, STG)                                               \
  {                                                                           \
    i32x8 af[4], bf[2];                                                       \
    _Pragma("unroll") for (int mq = 0; mq < 4; ++mq)                          \
        LDFRAG(af[mq], p * 65536, wr * 128 + (MH) * 64 + mq * 16 + lr);       \
    _Pragma("unroll") for (int nq = 0; nq < 2; ++nq)                          \
        LDFRAG(bf[nq], p * 65536 + 32768,                                     \
               wc * 64 + (NH) * 32 + nq * 16 + lr);                           \
    PRE;                                                                      \
    STG;                                                                      \
    __builtin_amdgcn_s_barrier();                                             \
    asm volatile("s_waitcnt lgkmcnt(0)" ::: "memory");                        \
    __builtin_amdgcn_sched_barrier(0);                                        \
    __builtin_amdgcn_s_setprio(1);                                            \
    _Pragma("unroll") for (int mq = 0; mq < 4; ++mq)                          \
      _Pragma("unroll") for (int nq = 0; nq < 2; ++nq)                        \
          acc[(MH) * 4 + mq][(NH) * 2 + nq] =                                 \
              __builtin_amdgcn_mfma_scale_f32_16x16x128_f8f6f4(               \
                  af[mq], bf[nq], acc[(MH) * 4 + mq][(NH) * 2 + nq], 0, 0, 0, \
                  127, 0, 127);                                               \
    __builtin_amdgcn_s_setprio(0);                                            \
    __builtin_amdgcn_s_barrier();                                             \
  }

__global__ __launch_bounds__(512, 2) void siglip_gemm(
    const unsigned char* __restrict__ A8,
    const unsigned char* __restrict__ B8,
    float* __restrict__ partials) {
  __shared__ unsigned char lds[131072];  // [buf0: A 32K | B 32K][buf1: ...]
  __shared__ float wsum[8];

  const int tid = threadIdx.x;
  const int wave = tid >> 6;
  const int lane = tid & 63;
  const int wr = wave >> 2;   // 0..1 -> 128-row strip
  const int wc = wave & 3;    // 0..3 -> 64-col strip
  const int wch = wc >> 1;    // which B half this wave reads
  const int brow = blockIdx.y;
  const int bcol = blockIdx.x;

  f32x4 acc[8][4];
#pragma unroll
  for (int m = 0; m < 8; ++m)
#pragma unroll
    for (int n = 0; n < 4; ++n) acc[m][n] = f32x4{0.f, 0.f, 0.f, 0.f};

  // Staging constants: thread covers row (wave*8 + lane/8) of each 64-row
  // j-block, fetching global chunk16 (lane&7) ^ (row&7) (inverse swizzle).
  const int s_row = wave * 8 + (lane >> 3);
  const int s_c = (((lane & 7) ^ ((lane >> 3) & 7)) << 4);
  const unsigned char* Aga = A8 + (size_t)(brow * BM) * K_DIM;
  const unsigned char* Bga = B8 + (size_t)(bcol * BM) * K_DIM;

  // Fragment-read constants: row/col = +lr, k byte = kch*32 (+0/16), XOR sw.
  const int lr = lane & 15;
  const int kch = lane >> 4;
  const int sw = (lr & 7) << 4;

  // Prologue: stage tile 0 into buf 0, full drain once.
  STAGE(0, 0, 0, 0, 1); STAGE(0, 0, 1, 0, 1);
  STAGE(0, 0, 0, 0, 0); STAGE(0, 0, 1, 0, 0);
  STAGE(0, 1, 0, 0, 0); STAGE(0, 1, 1, 0, 0);
  STAGE(0, 1, 0, 0, 1); STAGE(0, 1, 1, 0, 1);
  asm volatile("s_waitcnt vmcnt(0)" ::: "memory");
  __builtin_amdgcn_s_barrier();

  for (int T = 0; T < NT; ++T) {
    const int p = T & 1;
    const int k0n = ((T + 1) & (NT - 1)) * BKB;
    const bool st = (T < NT - 1);
    // ph1: stage A0',B0' of tile T+1 into buf p^1 (freed after iter T-1 ph4)
    PHASE(0, 0, ,
          if (st) { STAGE(p ^ 1, 0, 0, k0n, 1); STAGE(p ^ 1, 0, 1, k0n, 1);
                    STAGE(p ^ 1, 0, 0, k0n, 0); STAGE(p ^ 1, 0, 1, k0n, 0); })
    // ph2: stage B1',A1'
    PHASE(1, 0, ,
          if (st) { STAGE(p ^ 1, 1, 0, k0n, 0); STAGE(p ^ 1, 1, 1, k0n, 0);
                    STAGE(p ^ 1, 1, 0, k0n, 1); STAGE(p ^ 1, 1, 1, k0n, 1); })
    PHASE(0, 1, , )
    // ph4: counted wait for tile T+1, then barrier -> next iter reads safe
    PHASE(1, 1, if (st) VMWAIT(), )
  }

  // Epilogue. C/D 16x16 map: col = lane&15, row = (lane>>4)*4 + r.
  const int rbase = brow * BM + wr * 128 + (lane >> 4) * 4;
  const int cbase = bcol * BM + wc * 64 + (lane & 15);
  float lsum;
  if (brow == bcol)
    lsum = softplus_sum<true>(acc, rbase, cbase);
  else
    lsum = softplus_sum<false>(acc, rbase, cbase);

#pragma unroll
  for (int off = 32; off > 0; off >>= 1) lsum += __shfl_down(lsum, off);
  if (lane == 0) wsum[wave] = lsum;
  __syncthreads();
  if (tid == 0) {
    float s = 0.f;
#pragma unroll
    for (int w = 0; w < 8; ++w) s += wsum[w];
    partials[blockIdx.y * gridDim.x + blockIdx.x] = s;
  }
}

__global__ void reduce_kernel(const float* __restrict__ partials, int n,
                              float* __restrict__ out) {
  __shared__ float s[256];
  float v = 0.f;
  for (int i = threadIdx.x; i < n; i += 256) v += partials[i];
  s[threadIdx.x] = v;
  __syncthreads();
  for (int off = 128; off > 0; off >>= 1) {
    if ((int)threadIdx.x < off) s[threadIdx.x] += s[threadIdx.x + off];
    __syncthreads();
  }
  if (threadIdx.x == 0) out[0] = s[0] / (float)B_DIM;
}

extern "C" void kernel_launch(void* const* d_in, const int* in_sizes, int n_in,
                              void* d_out, int out_size, void* d_ws, size_t ws_size,
                              hipStream_t stream) {
  const float* emb1 = (const float*)d_in[0];
  const float* emb2 = (const float*)d_in[1];

  unsigned char* A8 = (unsigned char*)d_ws;                // 8 MB
  unsigned char* B8 = A8 + (size_t)B_DIM * K_DIM;          // 8 MB
  float* partials = (float*)(B8 + (size_t)B_DIM * K_DIM);  // 4 KB

  const int n8 = B_DIM * K_DIM / 8;
  const float INV_T = 1.0f / 0.07f;
  cvt_fp8_kernel<<<1024, 256, 0, stream>>>(emb1, (unsigned int*)A8, n8, INV_T);
  cvt_fp8_kernel<<<1024, 256, 0, stream>>>(emb2, (unsigned int*)B8, n8, 1.0f);

  dim3 grid(B_DIM / BM, B_DIM / BM);  // 32 x 32
  siglip_gemm<<<grid, 512, 0, stream>>>(A8, B8, partials);

  const int nparts = (B_DIM / BM) * (B_DIM / BM);
  reduce_kernel<<<1, 256, 0, stream>>>(partials, nparts, (float*)d_out);
}

// Round 5
// 1125.379 us; speedup vs baseline: 1.0005x; 1.0005x over previous
//
#include <hip/hip_runtime.h>

// SigLIP contrastive loss:
//   logits = emb1 @ emb2^T / 0.07           [B,B], B=8192, D=1024
//   loss = ( sum_i softplus(-l_ii) + sum_{i!=j} softplus(l_ij) ) / B
// R4: fix R3's register-spill disaster. __launch_bounds__(512,2) capped the
// unified VGPR+AGPR budget at 256/wave while the kernel needs ~280 ->
// 2.3 GB/dispatch scratch writes. LDS (128 KiB) limits us to 1 block/CU
// anyway, so declare (512,1) and let acc+frags live in registers.

#define B_DIM 8192
#define K_DIM 1024
#define BM 256
#define BKB 128                // K bytes per K-tile (fp8 elems)
#define NT (K_DIM / BKB)       // 8 K-tiles

typedef int i32x4 __attribute__((ext_vector_type(4)));
typedef int i32x8 __attribute__((ext_vector_type(8)));
typedef float f32x4 __attribute__((ext_vector_type(4)));

// f32 -> OCP e4m3 (hardware cvt, saturating), 8 elems/thread/iter.
__global__ void cvt_fp8_kernel(const float* __restrict__ in,
                               unsigned int* __restrict__ out, int n8,
                               float scale) {
  int i = blockIdx.x * blockDim.x + threadIdx.x;
  int stride = gridDim.x * blockDim.x;
  const float4* in4 = (const float4*)in;
  uint2* out2 = (uint2*)out;
  for (; i < n8; i += stride) {
    float4 v0 = in4[2 * i];
    float4 v1 = in4[2 * i + 1];
    unsigned int w0 = 0, w1 = 0;
    w0 = __builtin_amdgcn_cvt_pk_fp8_f32(v0.x * scale, v0.y * scale, w0, 0);
    w0 = __builtin_amdgcn_cvt_pk_fp8_f32(v0.z * scale, v0.w * scale, w0, 1);
    w1 = __builtin_amdgcn_cvt_pk_fp8_f32(v1.x * scale, v1.y * scale, w1, 0);
    w1 = __builtin_amdgcn_cvt_pk_fp8_f32(v1.z * scale, v1.w * scale, w1, 1);
    out2[i] = make_uint2(w0, w1);
  }
}

// Cheap softplus accumulate: softplus(x) = max(x,0) + log(1+exp(-|x|)).
template <bool DIAG>
__device__ __forceinline__ float softplus_sum(const f32x4 (&acc)[8][4],
                                              int rbase, int cbase) {
  float lin = 0.f, cor = 0.f;
#pragma unroll
  for (int m = 0; m < 8; ++m) {
#pragma unroll
    for (int n = 0; n < 4; ++n) {
#pragma unroll
      for (int r = 0; r < 4; ++r) {
        float x = acc[m][n][r];
        if (DIAG) {
          int row = rbase + m * 16 + r;
          int col = cbase + n * 16;
          if (row == col) x = -x;  // diagonal: softplus(-l_ii)
        }
        lin += fmaxf(x, 0.f);
        cor += __logf(1.f + __expf(-fabsf(x)));
      }
    }
  }
  return lin + cor;
}

// Stage one half-tile slice j: 512 threads x 16B, pre-swizzled global source
// (chunk16 ^= row&7) so linear global_load_lds lands the swizzled layout.
#define STAGE(BUF, HALF, J, K0, ISA)                                          \
  __builtin_amdgcn_global_load_lds(                                           \
      (const __attribute__((address_space(1))) void*)(const void*)(           \
          ((ISA) ? Aga : Bga) +                                               \
          (size_t)((HALF) * 128 + (J) * 64 + s_row) * K_DIM + (K0) + s_c),    \
      (__attribute__((address_space(3))) void*)(void*)(lds + (BUF) * 65536 +  \
          ((ISA) ? 0 : 32768) + (HALF) * 16384 + (J) * 8192 + wave * 1024),   \
      16, 0, 0)

// Load one 16x16x128 fp8 fragment (32B/lane) from swizzled LDS.
#define LDFRAG(OUT, BASEOFF, ROW)                                             \
  {                                                                           \
    const unsigned char* _b = lds + (BASEOFF) + (unsigned)(ROW) * 128;        \
    i32x4 _lo = *(const i32x4*)(_b + ((kch * 32) ^ sw));                      \
    i32x4 _hi = *(const i32x4*)(_b + ((kch * 32 + 16) ^ sw));                 \
    OUT = __builtin_shufflevector(_lo, _hi, 0, 1, 2, 3, 4, 5, 6, 7);          \
  }

// Group-specific counted vmcnt gating tile T+1 (issue order A0,B0 | B1,A1):
// (wr0,wch0) needs A0,B0 -> vmcnt(4); (wr0,wch1) A0,B1 -> vmcnt(2);
// wr1 needs A1 (last) -> vmcnt(0). Sits before a barrier so all waves' slices
// are resident before any wave reads (vmcnt is per-wave).
#define VMWAIT()                                                              \
  if (wr == 0) {                                                              \
    if (wch == 0) asm volatile("s_waitcnt vmcnt(4)" ::: "memory");            \
    else          asm volatile("s_waitcnt vmcnt(2)" ::: "memory");            \
  } else          asm volatile("s_waitcnt vmcnt(0)" ::: "memory")

// One phase: quadrant (MH,NH). ds_reads -> [PRE] -> [STG] -> barrier ->
// lgkm(0) -> 8 MFMA (setprio-wrapped) -> barrier.
#define PHASE(MH, NH, PRE, STG)                                               \
  {                                                                           \
    i32x8 af[4], bf[2];                                                       \
    _Pragma("unroll") for (int mq = 0; mq < 4; ++mq)                          \
        LDFRAG(af[mq], p * 65536, wr * 128 + (MH) * 64 + mq * 16 + lr);       \
    _Pragma("unroll") for (int nq = 0; nq < 2; ++nq)                          \
        LDFRAG(bf[nq], p * 65536 + 32768,                                     \
               wc * 64 + (NH) * 32 + nq * 16 + lr);                           \
    PRE;                                                                      \
    STG;                                                                      \
    __builtin_amdgcn_s_barrier();                                             \
    asm volatile("s_waitcnt lgkmcnt(0)" ::: "memory");                        \
    __builtin_amdgcn_sched_barrier(0);                                        \
    __builtin_amdgcn_s_setprio(1);                                            \
    _Pragma("unroll") for (int mq = 0; mq < 4; ++mq)                          \
      _Pragma("unroll") for (int nq = 0; nq < 2; ++nq)                        \
          acc[(MH) * 4 + mq][(NH) * 2 + nq] =                                 \
              __builtin_amdgcn_mfma_scale_f32_16x16x128_f8f6f4(               \
                  af[mq], bf[nq], acc[(MH) * 4 + mq][(NH) * 2 + nq], 0, 0, 0, \
                  127, 0, 127);                                               \
    __builtin_amdgcn_s_setprio(0);                                            \
    __builtin_amdgcn_s_barrier();                                             \
  }

__global__ __launch_bounds__(512, 1) void siglip_gemm(
    const unsigned char* __restrict__ A8,
    const unsigned char* __restrict__ B8,
    float* __restrict__ partials) {
  __shared__ unsigned char lds[131072];  // [buf0: A 32K | B 32K][buf1: ...]
  __shared__ float wsum[8];

  const int tid = threadIdx.x;
  const int wave = tid >> 6;
  const int lane = tid & 63;
  const int wr = wave >> 2;   // 0..1 -> 128-row strip
  const int wc = wave & 3;    // 0..3 -> 64-col strip
  const int wch = wc >> 1;    // which B half this wave reads
  const int brow = blockIdx.y;
  const int bcol = blockIdx.x;

  f32x4 acc[8][4];
#pragma unroll
  for (int m = 0; m < 8; ++m)
#pragma unroll
    for (int n = 0; n < 4; ++n) acc[m][n] = f32x4{0.f, 0.f, 0.f, 0.f};

  // Staging constants: thread covers row (wave*8 + lane/8) of each 64-row
  // j-block, fetching global chunk16 (lane&7) ^ (row&7) (inverse swizzle).
  const int s_row = wave * 8 + (lane >> 3);
  const int s_c = (((lane & 7) ^ ((lane >> 3) & 7)) << 4);
  const unsigned char* Aga = A8 + (size_t)(brow * BM) * K_DIM;
  const unsigned char* Bga = B8 + (size_t)(bcol * BM) * K_DIM;

  // Fragment-read constants: row/col = +lr, k byte = kch*32 (+0/16), XOR sw.
  const int lr = lane & 15;
  const int kch = lane >> 4;
  const int sw = (lr & 7) << 4;

  // Prologue: stage tile 0 into buf 0, full drain once.
  STAGE(0, 0, 0, 0, 1); STAGE(0, 0, 1, 0, 1);
  STAGE(0, 0, 0, 0, 0); STAGE(0, 0, 1, 0, 0);
  STAGE(0, 1, 0, 0, 0); STAGE(0, 1, 1, 0, 0);
  STAGE(0, 1, 0, 0, 1); STAGE(0, 1, 1, 0, 1);
  asm volatile("s_waitcnt vmcnt(0)" ::: "memory");
  __builtin_amdgcn_s_barrier();

  for (int T = 0; T < NT; ++T) {
    const int p = T & 1;
    const int k0n = ((T + 1) & (NT - 1)) * BKB;
    const bool st = (T < NT - 1);
    // ph1: stage A0',B0' of tile T+1 into buf p^1 (freed after iter T-1 ph4)
    PHASE(0, 0, ,
          if (st) { STAGE(p ^ 1, 0, 0, k0n, 1); STAGE(p ^ 1, 0, 1, k0n, 1);
                    STAGE(p ^ 1, 0, 0, k0n, 0); STAGE(p ^ 1, 0, 1, k0n, 0); })
    // ph2: stage B1',A1'
    PHASE(1, 0, ,
          if (st) { STAGE(p ^ 1, 1, 0, k0n, 0); STAGE(p ^ 1, 1, 1, k0n, 0);
                    STAGE(p ^ 1, 1, 0, k0n, 1); STAGE(p ^ 1, 1, 1, k0n, 1); })
    PHASE(0, 1, , )
    // ph4: counted wait for tile T+1, then barrier -> next iter reads safe
    PHASE(1, 1, if (st) VMWAIT(), )
  }

  // Epilogue. C/D 16x16 map: col = lane&15, row = (lane>>4)*4 + r.
  const int rbase = brow * BM + wr * 128 + (lane >> 4) * 4;
  const int cbase = bcol * BM + wc * 64 + (lane & 15);
  float lsum;
  if (brow == bcol)
    lsum = softplus_sum<true>(acc, rbase, cbase);
  else
    lsum = softplus_sum<false>(acc, rbase, cbase);

#pragma unroll
  for (int off = 32; off > 0; off >>= 1) lsum += __shfl_down(lsum, off);
  if (lane == 0) wsum[wave] = lsum;
  __syncthreads();
  if (tid == 0) {
    float s = 0.f;
#pragma unroll
    for (int w = 0; w < 8; ++w) s += wsum[w];
    partials[blockIdx.y * gridDim.x + blockIdx.x] = s;
  }
}

__global__ void reduce_kernel(const float* __restrict__ partials, int n,
                              float* __restrict__ out) {
  __shared__ float s[256];
  float v = 0.f;
  for (int i = threadIdx.x; i < n; i += 256) v += partials[i];
  s[threadIdx.x] = v;
  __syncthreads();
  for (int off = 128; off > 0; off >>= 1) {
    if ((int)threadIdx.x < off) s[threadIdx.x] += s[threadIdx.x + off];
    __syncthreads();
  }
  if (threadIdx.x == 0) out[0] = s[0] / (float)B_DIM;
}

extern "C" void kernel_launch(void* const* d_in, const int* in_sizes, int n_in,
                              void* d_out, int out_size, void* d_ws, size_t ws_size,
                              hipStream_t stream) {
  const float* emb1 = (const float*)d_in[0];
  const float* emb2 = (const float*)d_in[1];

  unsigned char* A8 = (unsigned char*)d_ws;                // 8 MB
  unsigned char* B8 = A8 + (size_t)B_DIM * K_DIM;          // 8 MB
  float* partials = (float*)(B8 + (size_t)B_DIM * K_DIM);  // 4 KB

  const int n8 = B_DIM * K_DIM / 8;
  const float INV_T = 1.0f / 0.07f;
  cvt_fp8_kernel<<<1024, 256, 0, stream>>>(emb1, (unsigned int*)A8, n8, INV_T);
  cvt_fp8_kernel<<<1024, 256, 0, stream>>>(emb2, (unsigned int*)B8, n8, 1.0f);

  dim3 grid(B_DIM / BM, B_DIM / BM);  // 32 x 32
  siglip_gemm<<<grid, 512, 0, stream>>>(A8, B8, partials);

  const int nparts = (B_DIM / BM) * (B_DIM / BM);
  reduce_kernel<<<1, 256, 0, stream>>>(partials, nparts, (float*)d_out);
}

// Round 6
// 228.291 us; speedup vs baseline: 4.9321x; 4.9296x over previous
//
#include <hip/hip_runtime.h>

// SigLIP contrastive loss:
//   logits = emb1 @ emb2^T / 0.07           [B,B], B=8192, D=1024
//   loss = ( sum_i softplus(-l_ii) + sum_{i!=j} softplus(l_ij) ) / B
// R6: kill the spill. 256x128 tile (acc 64 VGPR/thread), linear LDS with
// contiguous 32B fragment reads (no shufflevector), triple-buffered LDS
// (3x48KB) with depth-2 prefetch and uniform vmcnt(6) (correct T4).

#define B_DIM 8192
#define K_DIM 1024
#define BM 256                 // tile rows
#define BN 128                 // tile cols
#define BKB 128                // K bytes per K-tile (fp8 elems)
#define NT (K_DIM / BKB)       // 8 K-tiles
#define BUFSZ 49152            // per-buffer LDS: A 32KB + B 16KB

typedef int i32x8 __attribute__((ext_vector_type(8)));
typedef float f32x4 __attribute__((ext_vector_type(4)));

// f32 -> OCP e4m3 (hardware cvt, saturating), 8 elems/thread/iter.
__global__ void cvt_fp8_kernel(const float* __restrict__ in,
                               unsigned int* __restrict__ out, int n8,
                               float scale) {
  int i = blockIdx.x * blockDim.x + threadIdx.x;
  int stride = gridDim.x * blockDim.x;
  const float4* in4 = (const float4*)in;
  uint2* out2 = (uint2*)out;
  for (; i < n8; i += stride) {
    float4 v0 = in4[2 * i];
    float4 v1 = in4[2 * i + 1];
    unsigned int w0 = 0, w1 = 0;
    w0 = __builtin_amdgcn_cvt_pk_fp8_f32(v0.x * scale, v0.y * scale, w0, 0);
    w0 = __builtin_amdgcn_cvt_pk_fp8_f32(v0.z * scale, v0.w * scale, w0, 1);
    w1 = __builtin_amdgcn_cvt_pk_fp8_f32(v1.x * scale, v1.y * scale, w1, 0);
    w1 = __builtin_amdgcn_cvt_pk_fp8_f32(v1.z * scale, v1.w * scale, w1, 1);
    out2[i] = make_uint2(w0, w1);
  }
}

// Cheap softplus accumulate: softplus(x) = max(x,0) + log(1+exp(-|x|)).
template <bool DIAG>
__device__ __forceinline__ float softplus_sum(const f32x4 (&acc)[4][4],
                                              int rbase, int cbase) {
  float lin = 0.f, cor = 0.f;
#pragma unroll
  for (int m = 0; m < 4; ++m) {
#pragma unroll
    for (int n = 0; n < 4; ++n) {
#pragma unroll
      for (int r = 0; r < 4; ++r) {
        float x = acc[m][n][r];
        if (DIAG) {
          int row = rbase + m * 16 + r;
          int col = cbase + n * 16;
          if (row == col) x = -x;  // diagonal: softplus(-l_ii)
        }
        lin += fmaxf(x, 0.f);
        cor += __logf(1.f + __expf(-fabsf(x)));
      }
    }
  }
  return lin + cor;
}

// Staging (linear LDS, global_load_lds width 16):
// thread covers row s_row = wave*8 + lane/8 of a 64-row block, byte chunk
// (lane&7)*16; LDS dest = blockbase + wave*1024 (+ lane*16 implicit).
#define STAGEA(SB, H, J, K0)                                                  \
  __builtin_amdgcn_global_load_lds(                                           \
      (const __attribute__((address_space(1))) void*)(const void*)(           \
          Aga + (size_t)((H) * 128 + (J) * 64 + s_row) * K_DIM + (K0) + s_ch),\
      (__attribute__((address_space(3))) void*)(void*)(                       \
          lds + (SB) + (H) * 16384 + (J) * 8192 + wave * 1024),               \
      16, 0, 0)
#define STAGEB(SB, H, K0)                                                     \
  __builtin_amdgcn_global_load_lds(                                           \
      (const __attribute__((address_space(1))) void*)(const void*)(           \
          Bga + (size_t)((H) * 64 + s_row) * K_DIM + (K0) + s_ch),            \
      (__attribute__((address_space(3))) void*)(void*)(                       \
          lds + (SB) + 32768 + (H) * 8192 + wave * 1024),                     \
      16, 0, 0)

// Contiguous 32B fragment loads (2x ds_read_b128, no shuffle).
#define LDA(OUT, ROW) \
  OUT = *(const i32x8*)(lds + rb + (unsigned)(ROW) * 128 + kb)
#define LDB(OUT, COL) \
  OUT = *(const i32x8*)(lds + rb + 32768 + (unsigned)(COL) * 128 + kb)

#define MFMA(AF, BF, M, N)                                                    \
  acc[M][N] = __builtin_amdgcn_mfma_scale_f32_16x16x128_f8f6f4(               \
      AF, BF, acc[M][N], 0, 0, 0, 127, 0, 127)

// One phase: quadrant (MH,NH). ds_reads -> [PRE] -> [STG] -> barrier ->
// lgkm(0) -> 4 MFMA (setprio-wrapped) -> barrier.
#define PHASE(MH, NH, PRE, STG)                                               \
  {                                                                           \
    i32x8 af0, af1, bf0, bf1;                                                 \
    LDA(af0, wr * 64 + (MH) * 32 + lr);                                       \
    LDA(af1, wr * 64 + (MH) * 32 + 16 + lr);                                  \
    LDB(bf0, wc * 64 + (NH) * 32 + lr);                                       \
    LDB(bf1, wc * 64 + (NH) * 32 + 16 + lr);                                  \
    PRE;                                                                      \
    STG;                                                                      \
    __builtin_amdgcn_s_barrier();                                             \
    asm volatile("s_waitcnt lgkmcnt(0)" ::: "memory");                        \
    __builtin_amdgcn_sched_barrier(0);                                        \
    __builtin_amdgcn_s_setprio(1);                                            \
    MFMA(af0, bf0, (MH)*2 + 0, (NH)*2 + 0);                                   \
    MFMA(af0, bf1, (MH)*2 + 0, (NH)*2 + 1);                                   \
    MFMA(af1, bf0, (MH)*2 + 1, (NH)*2 + 0);                                   \
    MFMA(af1, bf1, (MH)*2 + 1, (NH)*2 + 1);                                   \
    __builtin_amdgcn_s_setprio(0);                                            \
    __builtin_amdgcn_s_barrier();                                             \
  }

__global__ __launch_bounds__(512, 1) void siglip_gemm(
    const unsigned char* __restrict__ A8,
    const unsigned char* __restrict__ B8,
    float* __restrict__ partials) {
  __shared__ unsigned char lds[3 * BUFSZ];  // 144 KB triple buffer
  __shared__ float wsum[8];

  const int tid = threadIdx.x;
  const int wave = tid >> 6;
  const int lane = tid & 63;
  const int wr = wave >> 1;  // 0..3 -> 64-row strip
  const int wc = wave & 1;   // 0..1 -> 64-col strip
  const int brow = blockIdx.y;
  const int bcol = blockIdx.x;

  f32x4 acc[4][4];
#pragma unroll
  for (int m = 0; m < 4; ++m)
#pragma unroll
    for (int n = 0; n < 4; ++n) acc[m][n] = f32x4{0.f, 0.f, 0.f, 0.f};

  const int s_row = wave * 8 + (lane >> 3);  // 0..63
  const int s_ch = (lane & 7) * 16;          // byte chunk
  const unsigned char* Aga = A8 + (size_t)(brow * BM) * K_DIM;
  const unsigned char* Bga = B8 + (size_t)(bcol * BN) * K_DIM;

  const int lr = lane & 15;          // frag row/col
  const int kb = (lane >> 4) * 32;   // frag k byte offset

  // Prologue: tile0 -> buf0, tile1 -> buf1 (12 issues), drain tile0 only.
  STAGEA(0, 0, 0, 0); STAGEA(0, 0, 1, 0); STAGEB(0, 0, 0);
  STAGEA(0, 1, 0, 0); STAGEA(0, 1, 1, 0); STAGEB(0, 1, 0);
  STAGEA(BUFSZ, 0, 0, BKB); STAGEA(BUFSZ, 0, 1, BKB); STAGEB(BUFSZ, 0, BKB);
  STAGEA(BUFSZ, 1, 0, BKB); STAGEA(BUFSZ, 1, 1, BKB); STAGEB(BUFSZ, 1, BKB);
  asm volatile("s_waitcnt vmcnt(6)" ::: "memory");
  __builtin_amdgcn_s_barrier();

  int rb = 0;  // read-buffer byte offset; stage buf = rb + 2*BUFSZ (mod 3)
  for (int T = 0; T < NT; ++T) {
    int sb = rb + 2 * BUFSZ;
    if (sb >= 3 * BUFSZ) sb -= 3 * BUFSZ;
    const int k2 = (T + 2) * BKB;
    const bool st = (T < NT - 2);
    // ph1: stage A-half0 of tile T+2 (+ B-half0)
    PHASE(0, 0, ,
          if (st) { STAGEA(sb, 0, 0, k2); STAGEA(sb, 0, 1, k2);
                    STAGEB(sb, 0, k2); })
    // ph2: stage A-half1 + B-half1
    PHASE(1, 0, ,
          if (st) { STAGEA(sb, 1, 0, k2); STAGEA(sb, 1, 1, k2);
                    STAGEB(sb, 1, k2); })
    PHASE(0, 1, , )
    // ph4: uniform counted wait -> tile T+1 fully resident for next iter
    PHASE(1, 1,
          if (st) { asm volatile("s_waitcnt vmcnt(6)" ::: "memory"); }
          else if (T < NT - 1) {
            asm volatile("s_waitcnt vmcnt(0)" ::: "memory");
          },
          )
    rb += BUFSZ;
    if (rb == 3 * BUFSZ) rb = 0;
  }

  // Epilogue. C/D 16x16 map: col = lane&15, row = (lane>>4)*4 + r.
  const int rbase = brow * BM + wr * 64 + (lane >> 4) * 4;
  const int cbase = bcol * BN + wc * 64 + (lane & 15);
  float lsum;
  if ((bcol >> 1) == brow)  // 256-row strip overlaps this 128-col strip
    lsum = softplus_sum<true>(acc, rbase, cbase);
  else
    lsum = softplus_sum<false>(acc, rbase, cbase);

#pragma unroll
  for (int off = 32; off > 0; off >>= 1) lsum += __shfl_down(lsum, off);
  if (lane == 0) wsum[wave] = lsum;
  __syncthreads();
  if (tid == 0) {
    float s = 0.f;
#pragma unroll
    for (int w = 0; w < 8; ++w) s += wsum[w];
    partials[blockIdx.y * gridDim.x + blockIdx.x] = s;
  }
}

__global__ void reduce_kernel(const float* __restrict__ partials, int n,
                              float* __restrict__ out) {
  __shared__ float s[256];
  float v = 0.f;
  for (int i = threadIdx.x; i < n; i += 256) v += partials[i];
  s[threadIdx.x] = v;
  __syncthreads();
  for (int off = 128; off > 0; off >>= 1) {
    if ((int)threadIdx.x < off) s[threadIdx.x] += s[threadIdx.x + off];
    __syncthreads();
  }
  if (threadIdx.x == 0) out[0] = s[0] / (float)B_DIM;
}

extern "C" void kernel_launch(void* const* d_in, const int* in_sizes, int n_in,
                              void* d_out, int out_size, void* d_ws, size_t ws_size,
                              hipStream_t stream) {
  const float* emb1 = (const float*)d_in[0];
  const float* emb2 = (const float*)d_in[1];

  unsigned char* A8 = (unsigned char*)d_ws;                // 8 MB
  unsigned char* B8 = A8 + (size_t)B_DIM * K_DIM;          // 8 MB
  float* partials = (float*)(B8 + (size_t)B_DIM * K_DIM);  // 8 KB

  const int n8 = B_DIM * K_DIM / 8;
  const float INV_T = 1.0f / 0.07f;
  cvt_fp8_kernel<<<1024, 256, 0, stream>>>(emb1, (unsigned int*)A8, n8, INV_T);
  cvt_fp8_kernel<<<1024, 256, 0, stream>>>(emb2, (unsigned int*)B8, n8, 1.0f);

  dim3 grid(B_DIM / BN, B_DIM / BM);  // 64 x 32
  siglip_gemm<<<grid, 512, 0, stream>>>(A8, B8, partials);

  const int nparts = (B_DIM / BM) * (B_DIM / BN);
  reduce_kernel<<<1, 256, 0, stream>>>(partials, nparts, (float*)d_out);
}

// Round 7
// 148.467 us; speedup vs baseline: 7.5839x; 1.5377x over previous
//
#include <hip/hip_runtime.h>

// SigLIP contrastive loss:
//   logits = emb1 @ emb2^T / 0.07           [B,B], B=8192, D=1024
//   loss = ( sum_i softplus(-l_ii) + sum_{i!=j} softplus(l_ij) ) / B
// R7: structural conflict-freedom. cvt writes fp8 operands in fragment-major
// bricks: per (panel, K-tile) brick = [fb][kch(0..3)][lr(0..15)][32B], so a
// wave's MFMA fragment read from LDS is base + lane*32 (contiguous 2048B,
// zero bank conflicts by construction) and staging is 1024B-linear
// global_load_lds slices. 2 phases/K-tile with B-fragment reuse (16B/MFMA).

#define B_DIM 8192
#define K_DIM 1024
#define BM 256                 // tile rows (A panel)
#define BN 128                 // tile cols (B panel)
#define BKB 128                // K bytes per K-tile
#define NT (K_DIM / BKB)       // 8 K-tiles
#define ABRICK 32768           // 256 rows x 128 B
#define BBRICK 16384           // 128 rows x 128 B
#define BUFSZ 49152            // LDS buffer: A 32K + B 16K

typedef int i32x8 __attribute__((ext_vector_type(8)));
typedef float f32x4 __attribute__((ext_vector_type(4)));

// f32 -> fp8 e4m3 brick permutation. One thread = 16 output bytes.
// Output index o decomposes: brick b = p*8+t, then [fb][kch][lr][h*16].
// Source: row = p*PANEL + fb*16 + lr, elem = t*128 + kch*32 + h*16.
template <int PANEL>
__global__ __launch_bounds__(256) void cvt_fp8_brick(
    const float* __restrict__ in, unsigned char* __restrict__ out,
    float scale) {
  constexpr int BRICK = PANEL * 128;
  const int i = blockIdx.x * blockDim.x + threadIdx.x;
  const int o = i * 16;
  const int b = o / BRICK;
  const int p = b >> 3, t = b & 7;
  const int w = o & (BRICK - 1);
  const int fb = w >> 11;
  const int kch = (w >> 9) & 3;
  const int lr = (w >> 5) & 15;
  const int h = (w >> 4) & 1;
  const int row = p * PANEL + fb * 16 + lr;
  const int kb = t * 128 + kch * 32 + h * 16;
  const float4* src = (const float4*)(in + (size_t)row * K_DIM + kb);
  float4 v0 = src[0], v1 = src[1], v2 = src[2], v3 = src[3];
  unsigned w0 = 0, w1 = 0, w2 = 0, w3 = 0;
  w0 = __builtin_amdgcn_cvt_pk_fp8_f32(v0.x * scale, v0.y * scale, w0, 0);
  w0 = __builtin_amdgcn_cvt_pk_fp8_f32(v0.z * scale, v0.w * scale, w0, 1);
  w1 = __builtin_amdgcn_cvt_pk_fp8_f32(v1.x * scale, v1.y * scale, w1, 0);
  w1 = __builtin_amdgcn_cvt_pk_fp8_f32(v1.z * scale, v1.w * scale, w1, 1);
  w2 = __builtin_amdgcn_cvt_pk_fp8_f32(v2.x * scale, v2.y * scale, w2, 0);
  w2 = __builtin_amdgcn_cvt_pk_fp8_f32(v2.z * scale, v2.w * scale, w2, 1);
  w3 = __builtin_amdgcn_cvt_pk_fp8_f32(v3.x * scale, v3.y * scale, w3, 0);
  w3 = __builtin_amdgcn_cvt_pk_fp8_f32(v3.z * scale, v3.w * scale, w3, 1);
  *(uint4*)(out + o) = make_uint4(w0, w1, w2, w3);
}

// Cheap softplus accumulate: softplus(x) = max(x,0) + log(1+exp(-|x|)).
template <bool DIAG>
__device__ __forceinline__ float softplus_sum(const f32x4 (&acc)[4][4],
                                              int rbase, int cbase) {
  float lin = 0.f, cor = 0.f;
#pragma unroll
  for (int m = 0; m < 4; ++m) {
#pragma unroll
    for (int n = 0; n < 4; ++n) {
#pragma unroll
      for (int r = 0; r < 4; ++r) {
        float x = acc[m][n][r];
        if (DIAG) {
          int row = rbase + m * 16 + r;
          int col = cbase + n * 16;
          if (row == col) x = -x;  // diagonal: softplus(-l_ii)
        }
        lin += fmaxf(x, 0.f);
        cor += __logf(1.f + __expf(-fabsf(x)));
      }
    }
  }
  return lin + cor;
}

// Staging: 48 linear 1024B slices per K-tile (A 32, B 16); wave w takes
// slice j*8+w. Source is brick-linear, dest is LDS-linear (lane*16 implicit).
#define STAGEA(SB, J, TI)                                                     \
  __builtin_amdgcn_global_load_lds(                                           \
      (const __attribute__((address_space(1))) void*)(const void*)(           \
          srcA + (size_t)(TI) * ABRICK + (J) * 8192),                         \
      (__attribute__((address_space(3))) void*)(void*)(                       \
          lds + (SB) + dA + (J) * 8192),                                      \
      16, 0, 0)
#define STAGEB(SB, J, TI)                                                     \
  __builtin_amdgcn_global_load_lds(                                           \
      (const __attribute__((address_space(1))) void*)(const void*)(           \
          srcB + (size_t)(TI) * BBRICK + (J) * 8192),                         \
      (__attribute__((address_space(3))) void*)(void*)(                       \
          lds + (SB) + dB + (J) * 8192),                                      \
      16, 0, 0)

// Fragment reads: contiguous 2048B per wave (2x ds_read_b128, conflict-free).
#define LDA(M) *(const i32x8*)(lds + rb + (wr * 4 + (M)) * 2048 + (lane << 5))
#define LDB(N) \
  *(const i32x8*)(lds + rb + 32768 + (wc * 4 + (N)) * 2048 + (lane << 5))

#define MFMA(AF, BF, M, N)                                                    \
  acc[M][N] = __builtin_amdgcn_mfma_scale_f32_16x16x128_f8f6f4(               \
      AF, BF, acc[M][N], 0, 0, 0, 127, 0, 127)

__global__ __launch_bounds__(512, 1) void siglip_gemm(
    const unsigned char* __restrict__ A8,
    const unsigned char* __restrict__ B8,
    float* __restrict__ partials) {
  __shared__ unsigned char lds[3 * BUFSZ];  // 144 KB triple buffer
  __shared__ float wsum[8];

  const int tid = threadIdx.x;
  const int wave = tid >> 6;
  const int lane = tid & 63;
  const int wr = wave >> 1;  // 0..3 -> 64-row strip
  const int wc = wave & 1;   // 0..1 -> 64-col strip
  const int brow = blockIdx.y;
  const int bcol = blockIdx.x;

  f32x4 acc[4][4];
#pragma unroll
  for (int m = 0; m < 4; ++m)
#pragma unroll
    for (int n = 0; n < 4; ++n) acc[m][n] = f32x4{0.f, 0.f, 0.f, 0.f};

  const unsigned char* srcA =
      A8 + (size_t)brow * (NT * ABRICK) + wave * 1024 + (lane << 4);
  const unsigned char* srcB =
      B8 + (size_t)bcol * (NT * BBRICK) + wave * 1024 + (lane << 4);
  const int dA = wave * 1024;
  const int dB = 32768 + wave * 1024;

  // Prologue: tile0 -> buf0, tile1 -> buf1, drain tile0 only (vmcnt 6).
  STAGEA(0, 0, 0); STAGEA(0, 1, 0); STAGEA(0, 2, 0); STAGEA(0, 3, 0);
  STAGEB(0, 0, 0); STAGEB(0, 1, 0);
  STAGEA(BUFSZ, 0, 1); STAGEA(BUFSZ, 1, 1);
  STAGEA(BUFSZ, 2, 1); STAGEA(BUFSZ, 3, 1);
  STAGEB(BUFSZ, 0, 1); STAGEB(BUFSZ, 1, 1);
  asm volatile("s_waitcnt vmcnt(6)" ::: "memory");
  __builtin_amdgcn_s_barrier();

  int rb = 0;  // read buffer; stage buffer = rb + 2*BUFSZ (mod 3)
  for (int T = 0; T < NT; ++T) {
    int sb = rb + 2 * BUFSZ;
    if (sb >= 3 * BUFSZ) sb -= 3 * BUFSZ;
    const bool st = (T < NT - 2);

    // ---- phase 0: B frags (held across phases) + A-half 0
    i32x8 b0 = LDB(0), b1 = LDB(1), b2 = LDB(2), b3 = LDB(3);
    i32x8 a0 = LDA(0), a1 = LDA(1);
    if (st) { STAGEA(sb, 0, T + 2); STAGEA(sb, 1, T + 2); STAGEB(sb, 0, T + 2); }
    __builtin_amdgcn_s_barrier();
    asm volatile("s_waitcnt lgkmcnt(0)" ::: "memory");
    __builtin_amdgcn_sched_barrier(0);
    __builtin_amdgcn_s_setprio(1);
    MFMA(a0, b0, 0, 0); MFMA(a0, b1, 0, 1); MFMA(a0, b2, 0, 2); MFMA(a0, b3, 0, 3);
    MFMA(a1, b0, 1, 0); MFMA(a1, b1, 1, 1); MFMA(a1, b2, 1, 2); MFMA(a1, b3, 1, 3);
    __builtin_amdgcn_s_setprio(0);
    __builtin_amdgcn_s_barrier();

    // ---- phase 1: A-half 1 (B reused from registers)
    a0 = LDA(2); a1 = LDA(3);
    if (st) { STAGEA(sb, 2, T + 2); STAGEA(sb, 3, T + 2); STAGEB(sb, 1, T + 2); }
    // Gate: tile T+1 (6 oldest loads) must be resident before next iter reads.
    if (st) asm volatile("s_waitcnt vmcnt(6)" ::: "memory");
    else if (T < NT - 1) asm volatile("s_waitcnt vmcnt(0)" ::: "memory");
    __builtin_amdgcn_s_barrier();
    asm volatile("s_waitcnt lgkmcnt(0)" ::: "memory");
    __builtin_amdgcn_sched_barrier(0);
    __builtin_amdgcn_s_setprio(1);
    MFMA(a0, b0, 2, 0); MFMA(a0, b1, 2, 1); MFMA(a0, b2, 2, 2); MFMA(a0, b3, 2, 3);
    MFMA(a1, b0, 3, 0); MFMA(a1, b1, 3, 1); MFMA(a1, b2, 3, 2); MFMA(a1, b3, 3, 3);
    __builtin_amdgcn_s_setprio(0);
    __builtin_amdgcn_s_barrier();

    rb += BUFSZ;
    if (rb == 3 * BUFSZ) rb = 0;
  }

  // Epilogue. C/D 16x16 map: col = lane&15, row = (lane>>4)*4 + r.
  const int rbase = brow * BM + wr * 64 + (lane >> 4) * 4;
  const int cbase = bcol * BN + wc * 64 + (lane & 15);
  float lsum;
  if ((bcol >> 1) == brow)  // this 128-col strip overlaps the 256-row strip
    lsum = softplus_sum<true>(acc, rbase, cbase);
  else
    lsum = softplus_sum<false>(acc, rbase, cbase);

#pragma unroll
  for (int off = 32; off > 0; off >>= 1) lsum += __shfl_down(lsum, off);
  if (lane == 0) wsum[wave] = lsum;
  __syncthreads();
  if (tid == 0) {
    float s = 0.f;
#pragma unroll
    for (int w = 0; w < 8; ++w) s += wsum[w];
    partials[blockIdx.y * gridDim.x + blockIdx.x] = s;
  }
}

__global__ void reduce_kernel(const float* __restrict__ partials, int n,
                              float* __restrict__ out) {
  __shared__ float s[256];
  float v = 0.f;
  for (int i = threadIdx.x; i < n; i += 256) v += partials[i];
  s[threadIdx.x] = v;
  __syncthreads();
  for (int off = 128; off > 0; off >>= 1) {
    if ((int)threadIdx.x < off) s[threadIdx.x] += s[threadIdx.x + off];
    __syncthreads();
  }
  if (threadIdx.x == 0) out[0] = s[0] / (float)B_DIM;
}

extern "C" void kernel_launch(void* const* d_in, const int* in_sizes, int n_in,
                              void* d_out, int out_size, void* d_ws, size_t ws_size,
                              hipStream_t stream) {
  const float* emb1 = (const float*)d_in[0];
  const float* emb2 = (const float*)d_in[1];

  unsigned char* A8 = (unsigned char*)d_ws;                // 8 MB (bricked)
  unsigned char* B8 = A8 + (size_t)B_DIM * K_DIM;          // 8 MB (bricked)
  float* partials = (float*)(B8 + (size_t)B_DIM * K_DIM);  // 8 KB

  const float INV_T = 1.0f / 0.07f;
  const int nthreads = B_DIM * K_DIM / 16;  // 16 out bytes per thread
  cvt_fp8_brick<BM><<<nthreads / 256, 256, 0, stream>>>(emb1, A8, INV_T);
  cvt_fp8_brick<BN><<<nthreads / 256, 256, 0, stream>>>(emb2, B8, 1.0f);

  dim3 grid(B_DIM / BN, B_DIM / BM);  // 64 x 32
  siglip_gemm<<<grid, 512, 0, stream>>>(A8, B8, partials);

  const int nparts = (B_DIM / BM) * (B_DIM / BN);
  reduce_kernel<<<1, 256, 0, stream>>>(partials, nparts, (float*)d_out);
}

// Round 8
// 126.405 us; speedup vs baseline: 8.9075x; 1.1745x over previous
//
#include <hip/hip_runtime.h>

// SigLIP contrastive loss:
//   logits = emb1 @ emb2^T / 0.07           [B,B], B=8192, D=1024
//   loss = ( sum_i softplus(-l_ii) + sum_{i!=j} softplus(l_ij) ) / B
// R8: true conflict-free fragment reads + single phase per K-tile.
// Brick layout per (panel, K-tile): [fb][h(0..1)][kch(0..3)][lr(0..15)][16B]
// -> a fragment's 64 lanes read lo/hi halves at lane*16 stride (canonical
// conflict-free). One phase per K-tile: 16 ds_read_b128 feed 16 MFMA
// (full 4x4 reuse, LDS ~1024 cyc/CU vs MFMA ~1100 cyc/SIMD balanced).

#define B_DIM 8192
#define K_DIM 1024
#define BM 256                 // tile rows (A panel)
#define BN 128                 // tile cols (B panel)
#define BKB 128                // K bytes per K-tile
#define NT (K_DIM / BKB)       // 8 K-tiles
#define ABRICK 32768           // 256 rows x 128 B
#define BBRICK 16384           // 128 rows x 128 B
#define BUFSZ 49152            // LDS buffer: A 32K + B 16K

typedef int i32x4 __attribute__((ext_vector_type(4)));
typedef int i32x8 __attribute__((ext_vector_type(8)));
typedef float f32x4 __attribute__((ext_vector_type(4)));

// f32 -> fp8 e4m3 brick permutation. One thread = 16 output bytes.
// Brick offset = fb*2048 + h*1024 + kch*256 + lr*16.
// Source: row = p*PANEL + fb*16 + lr, k byte = t*128 + kch*32 + h*16.
template <int PANEL>
__global__ __launch_bounds__(256) void cvt_fp8_brick(
    const float* __restrict__ in, unsigned char* __restrict__ out,
    float scale) {
  constexpr int BRICK = PANEL * 128;
  const int i = blockIdx.x * blockDim.x + threadIdx.x;
  const int o = i * 16;
  const int b = o / BRICK;
  const int p = b >> 3, t = b & 7;        // NT==8 bricks per panel strip
  const int w = o & (BRICK - 1);
  const int fb = w >> 11;
  const int h = (w >> 10) & 1;
  const int kch = (w >> 8) & 3;
  const int lr = (w >> 4) & 15;
  const int row = p * PANEL + fb * 16 + lr;
  const int kb = t * 128 + kch * 32 + h * 16;
  const float4* src = (const float4*)(in + (size_t)row * K_DIM + kb);
  float4 v0 = src[0], v1 = src[1], v2 = src[2], v3 = src[3];
  unsigned w0 = 0, w1 = 0, w2 = 0, w3 = 0;
  w0 = __builtin_amdgcn_cvt_pk_fp8_f32(v0.x * scale, v0.y * scale, w0, 0);
  w0 = __builtin_amdgcn_cvt_pk_fp8_f32(v0.z * scale, v0.w * scale, w0, 1);
  w1 = __builtin_amdgcn_cvt_pk_fp8_f32(v1.x * scale, v1.y * scale, w1, 0);
  w1 = __builtin_amdgcn_cvt_pk_fp8_f32(v1.z * scale, v1.w * scale, w1, 1);
  w2 = __builtin_amdgcn_cvt_pk_fp8_f32(v2.x * scale, v2.y * scale, w2, 0);
  w2 = __builtin_amdgcn_cvt_pk_fp8_f32(v2.z * scale, v2.w * scale, w2, 1);
  w3 = __builtin_amdgcn_cvt_pk_fp8_f32(v3.x * scale, v3.y * scale, w3, 0);
  w3 = __builtin_amdgcn_cvt_pk_fp8_f32(v3.z * scale, v3.w * scale, w3, 1);
  *(uint4*)(out + o) = make_uint4(w0, w1, w2, w3);
}

// Cheap softplus accumulate: softplus(x) = max(x,0) + log(1+exp(-|x|)).
template <bool DIAG>
__device__ __forceinline__ float softplus_sum(const f32x4 (&acc)[4][4],
                                              int rbase, int cbase) {
  float lin = 0.f, cor = 0.f;
#pragma unroll
  for (int m = 0; m < 4; ++m) {
#pragma unroll
    for (int n = 0; n < 4; ++n) {
#pragma unroll
      for (int r = 0; r < 4; ++r) {
        float x = acc[m][n][r];
        if (DIAG) {
          int row = rbase + m * 16 + r;
          int col = cbase + n * 16;
          if (row == col) x = -x;  // diagonal: softplus(-l_ii)
        }
        lin += fmaxf(x, 0.f);
        cor += __logf(1.f + __expf(-fabsf(x)));
      }
    }
  }
  return lin + cor;
}

// Staging: 48KB per K-tile as 48 linear 1024B slices (A 32, B 16); wave w
// takes slice j*8+w. Brick source and LDS dest are both linear.
#define STAGEA(SB, J, TI)                                                     \
  __builtin_amdgcn_global_load_lds(                                           \
      (const __attribute__((address_space(1))) void*)(const void*)(           \
          srcA + (size_t)(TI) * ABRICK + (J) * 8192),                         \
      (__attribute__((address_space(3))) void*)(void*)(                       \
          lds + (SB) + dA + (J) * 8192),                                      \
      16, 0, 0)
#define STAGEB(SB, J, TI)                                                     \
  __builtin_amdgcn_global_load_lds(                                           \
      (const __attribute__((address_space(1))) void*)(const void*)(           \
          srcB + (size_t)(TI) * BBRICK + (J) * 8192),                         \
      (__attribute__((address_space(3))) void*)(void*)(                       \
          lds + (SB) + dB + (J) * 8192),                                      \
      16, 0, 0)

// Fragment read: two conflict-free ds_read_b128 (lane*16 stride) + combine.
#define LDA(OUT, M)                                                           \
  {                                                                           \
    const unsigned char* _b =                                                 \
        lds + rb + ((wr * 4 + (M)) << 11) + (lane << 4);                      \
    i32x4 _lo = *(const i32x4*)(_b);                                          \
    i32x4 _hi = *(const i32x4*)(_b + 1024);                                   \
    OUT = __builtin_shufflevector(_lo, _hi, 0, 1, 2, 3, 4, 5, 6, 7);          \
  }
#define LDB(OUT, N)                                                           \
  {                                                                           \
    const unsigned char* _b =                                                 \
        lds + rb + 32768 + ((wc * 4 + (N)) << 11) + (lane << 4);              \
    i32x4 _lo = *(const i32x4*)(_b);                                          \
    i32x4 _hi = *(const i32x4*)(_b + 1024);                                   \
    OUT = __builtin_shufflevector(_lo, _hi, 0, 1, 2, 3, 4, 5, 6, 7);          \
  }

#define MFMA(AF, BF, M, N)                                                    \
  acc[M][N] = __builtin_amdgcn_mfma_scale_f32_16x16x128_f8f6f4(               \
      AF, BF, acc[M][N], 0, 0, 0, 127, 0, 127)

__global__ __launch_bounds__(512, 1) void siglip_gemm(
    const unsigned char* __restrict__ A8,
    const unsigned char* __restrict__ B8,
    float* __restrict__ partials) {
  __shared__ unsigned char lds[3 * BUFSZ];  // 144 KB triple buffer
  __shared__ float wsum[8];

  const int tid = threadIdx.x;
  const int wave = tid >> 6;
  const int lane = tid & 63;
  const int wr = wave >> 1;  // 0..3 -> 64-row strip
  const int wc = wave & 1;   // 0..1 -> 64-col strip
  const int brow = blockIdx.y;
  const int bcol = blockIdx.x;

  f32x4 acc[4][4];
#pragma unroll
  for (int m = 0; m < 4; ++m)
#pragma unroll
    for (int n = 0; n < 4; ++n) acc[m][n] = f32x4{0.f, 0.f, 0.f, 0.f};

  const unsigned char* srcA =
      A8 + (size_t)brow * (NT * ABRICK) + wave * 1024 + (lane << 4);
  const unsigned char* srcB =
      B8 + (size_t)bcol * (NT * BBRICK) + wave * 1024 + (lane << 4);
  const int dA = wave * 1024;
  const int dB = 32768 + wave * 1024;

  // Prologue: tile0 -> buf0, tile1 -> buf1, drain tile0 only (vmcnt 6).
  STAGEA(0, 0, 0); STAGEA(0, 1, 0); STAGEA(0, 2, 0); STAGEA(0, 3, 0);
  STAGEB(0, 0, 0); STAGEB(0, 1, 0);
  STAGEA(BUFSZ, 0, 1); STAGEA(BUFSZ, 1, 1);
  STAGEA(BUFSZ, 2, 1); STAGEA(BUFSZ, 3, 1);
  STAGEB(BUFSZ, 0, 1); STAGEB(BUFSZ, 1, 1);
  asm volatile("s_waitcnt vmcnt(6)" ::: "memory");
  __builtin_amdgcn_s_barrier();

  int rb = 0;  // read buffer; stage buffer = rb + 2*BUFSZ (mod 3)
  for (int T = 0; T < NT; ++T) {
    int sb = rb + 2 * BUFSZ;
    if (sb >= 3 * BUFSZ) sb -= 3 * BUFSZ;

    // Issue all fragment reads for this K-tile (16x ds_read_b128).
    i32x8 b0, b1, b2, b3, a0, a1, a2, a3;
    LDB(b0, 0); LDB(b1, 1); LDB(b2, 2); LDB(b3, 3);
    LDA(a0, 0); LDA(a1, 1); LDA(a2, 2); LDA(a3, 3);

    // Stage tile T+2; gate tile T+1 residency before next iter's reads.
    if (T < NT - 2) {
      STAGEA(sb, 0, T + 2); STAGEA(sb, 1, T + 2);
      STAGEA(sb, 2, T + 2); STAGEA(sb, 3, T + 2);
      STAGEB(sb, 0, T + 2); STAGEB(sb, 1, T + 2);
      asm volatile("s_waitcnt vmcnt(6)" ::: "memory");
    } else if (T == NT - 2) {
      asm volatile("s_waitcnt vmcnt(0)" ::: "memory");
    }
    __builtin_amdgcn_s_barrier();
    asm volatile("s_waitcnt lgkmcnt(0)" ::: "memory");
    __builtin_amdgcn_sched_barrier(0);
    __builtin_amdgcn_s_setprio(1);
    MFMA(a0, b0, 0, 0); MFMA(a0, b1, 0, 1); MFMA(a0, b2, 0, 2); MFMA(a0, b3, 0, 3);
    MFMA(a1, b0, 1, 0); MFMA(a1, b1, 1, 1); MFMA(a1, b2, 1, 2); MFMA(a1, b3, 1, 3);
    MFMA(a2, b0, 2, 0); MFMA(a2, b1, 2, 1); MFMA(a2, b2, 2, 2); MFMA(a2, b3, 2, 3);
    MFMA(a3, b0, 3, 0); MFMA(a3, b1, 3, 1); MFMA(a3, b2, 3, 2); MFMA(a3, b3, 3, 3);
    __builtin_amdgcn_s_setprio(0);
    __builtin_amdgcn_s_barrier();

    rb += BUFSZ;
    if (rb == 3 * BUFSZ) rb = 0;
  }

  // Epilogue. C/D 16x16 map: col = lane&15, row = (lane>>4)*4 + r.
  const int rbase = brow * BM + wr * 64 + (lane >> 4) * 4;
  const int cbase = bcol * BN + wc * 64 + (lane & 15);
  float lsum;
  if ((bcol >> 1) == brow)  // this 128-col strip overlaps the 256-row strip
    lsum = softplus_sum<true>(acc, rbase, cbase);
  else
    lsum = softplus_sum<false>(acc, rbase, cbase);

#pragma unroll
  for (int off = 32; off > 0; off >>= 1) lsum += __shfl_down(lsum, off);
  if (lane == 0) wsum[wave] = lsum;
  __syncthreads();
  if (tid == 0) {
    float s = 0.f;
#pragma unroll
    for (int w = 0; w < 8; ++w) s += wsum[w];
    partials[blockIdx.y * gridDim.x + blockIdx.x] = s;
  }
}

__global__ void reduce_kernel(const float* __restrict__ partials, int n,
                              float* __restrict__ out) {
  __shared__ float s[256];
  float v = 0.f;
  for (int i = threadIdx.x; i < n; i += 256) v += partials[i];
  s[threadIdx.x] = v;
  __syncthreads();
  for (int off = 128; off > 0; off >>= 1) {
    if ((int)threadIdx.x < off) s[threadIdx.x] += s[threadIdx.x + off];
    __syncthreads();
  }
  if (threadIdx.x == 0) out[0] = s[0] / (float)B_DIM;
}

extern "C" void kernel_launch(void* const* d_in, const int* in_sizes, int n_in,
                              void* d_out, int out_size, void* d_ws, size_t ws_size,
                              hipStream_t stream) {
  const float* emb1 = (const float*)d_in[0];
  const float* emb2 = (const float*)d_in[1];

  unsigned char* A8 = (unsigned char*)d_ws;                // 8 MB (bricked)
  unsigned char* B8 = A8 + (size_t)B_DIM * K_DIM;          // 8 MB (bricked)
  float* partials = (float*)(B8 + (size_t)B_DIM * K_DIM);  // 8 KB

  const float INV_T = 1.0f / 0.07f;
  const int nthreads = B_DIM * K_DIM / 16;  // 16 out bytes per thread
  cvt_fp8_brick<BM><<<nthreads / 256, 256, 0, stream>>>(emb1, A8, INV_T);
  cvt_fp8_brick<BN><<<nthreads / 256, 256, 0, stream>>>(emb2, B8, 1.0f);

  dim3 grid(B_DIM / BN, B_DIM / BM);  // 64 x 32
  siglip_gemm<<<grid, 512, 0, stream>>>(A8, B8, partials);

  const int nparts = (B_DIM / BM) * (B_DIM / BN);
  reduce_kernel<<<1, 256, 0, stream>>>(partials, nparts, (float*)d_out);
}

// Round 9
// 121.958 us; speedup vs baseline: 9.2323x; 1.0365x over previous
//
#include <hip/hip_runtime.h>

// SigLIP contrastive loss:
//   logits = emb1 @ emb2^T / 0.07           [B,B], B=8192, D=1024
//   loss = ( sum_i softplus(-l_ii) + sum_{i!=j} softplus(l_ij) ) / B
// R9: unleash the scheduler. R8's forced lgkmcnt(0)+sched_barrier before the
// MFMA cluster and 2 barriers/K-tile serialized read-phase vs MFMA-phase
// (4200 cyc/K-tile vs 1100 MFMA). Plain C++ ds_reads -> compiler emits
// fine-grained counted lgkmcnt; ONE barrier per K-tile (after MFMA; staging
// at T targets slot of T-1, consumed before end-of-iter-(T-1) barrier).
// Data plane unchanged: bricked fp8, conflict-free lane*16 reads, triple
// buffer, per-wave vmcnt(6).

#define B_DIM 8192
#define K_DIM 1024
#define BM 256                 // tile rows (A panel)
#define BN 128                 // tile cols (B panel)
#define BKB 128                // K bytes per K-tile
#define NT (K_DIM / BKB)       // 8 K-tiles
#define ABRICK 32768           // 256 rows x 128 B
#define BBRICK 16384           // 128 rows x 128 B
#define BUFSZ 49152            // LDS buffer: A 32K + B 16K

typedef int i32x4 __attribute__((ext_vector_type(4)));
typedef int i32x8 __attribute__((ext_vector_type(8)));
typedef float f32x4 __attribute__((ext_vector_type(4)));

// f32 -> fp8 e4m3 brick permutation. One thread = 16 output bytes.
// Brick offset = fb*2048 + h*1024 + kch*256 + lr*16.
// Source: row = p*PANEL + fb*16 + lr, k byte = t*128 + kch*32 + h*16.
template <int PANEL>
__global__ __launch_bounds__(256) void cvt_fp8_brick(
    const float* __restrict__ in, unsigned char* __restrict__ out,
    float scale) {
  constexpr int BRICK = PANEL * 128;
  const int i = blockIdx.x * blockDim.x + threadIdx.x;
  const int o = i * 16;
  const int b = o / BRICK;
  const int p = b >> 3, t = b & 7;        // NT==8 bricks per panel strip
  const int w = o & (BRICK - 1);
  const int fb = w >> 11;
  const int h = (w >> 10) & 1;
  const int kch = (w >> 8) & 3;
  const int lr = (w >> 4) & 15;
  const int row = p * PANEL + fb * 16 + lr;
  const int kb = t * 128 + kch * 32 + h * 16;
  const float4* src = (const float4*)(in + (size_t)row * K_DIM + kb);
  float4 v0 = src[0], v1 = src[1], v2 = src[2], v3 = src[3];
  unsigned w0 = 0, w1 = 0, w2 = 0, w3 = 0;
  w0 = __builtin_amdgcn_cvt_pk_fp8_f32(v0.x * scale, v0.y * scale, w0, 0);
  w0 = __builtin_amdgcn_cvt_pk_fp8_f32(v0.z * scale, v0.w * scale, w0, 1);
  w1 = __builtin_amdgcn_cvt_pk_fp8_f32(v1.x * scale, v1.y * scale, w1, 0);
  w1 = __builtin_amdgcn_cvt_pk_fp8_f32(v1.z * scale, v1.w * scale, w1, 1);
  w2 = __builtin_amdgcn_cvt_pk_fp8_f32(v2.x * scale, v2.y * scale, w2, 0);
  w2 = __builtin_amdgcn_cvt_pk_fp8_f32(v2.z * scale, v2.w * scale, w2, 1);
  w3 = __builtin_amdgcn_cvt_pk_fp8_f32(v3.x * scale, v3.y * scale, w3, 0);
  w3 = __builtin_amdgcn_cvt_pk_fp8_f32(v3.z * scale, v3.w * scale, w3, 1);
  *(uint4*)(out + o) = make_uint4(w0, w1, w2, w3);
}

// Cheap softplus accumulate: softplus(x) = max(x,0) + log(1+exp(-|x|)).
template <bool DIAG>
__device__ __forceinline__ float softplus_sum(const f32x4 (&acc)[4][4],
                                              int rbase, int cbase) {
  float lin = 0.f, cor = 0.f;
#pragma unroll
  for (int m = 0; m < 4; ++m) {
#pragma unroll
    for (int n = 0; n < 4; ++n) {
#pragma unroll
      for (int r = 0; r < 4; ++r) {
        float x = acc[m][n][r];
        if (DIAG) {
          int row = rbase + m * 16 + r;
          int col = cbase + n * 16;
          if (row == col) x = -x;  // diagonal: softplus(-l_ii)
        }
        lin += fmaxf(x, 0.f);
        cor += __logf(1.f + __expf(-fabsf(x)));
      }
    }
  }
  return lin + cor;
}

// Staging: 48KB per K-tile as 48 linear 1024B slices (A 32, B 16); wave w
// takes slice j*8+w. Brick source and LDS dest are both linear.
#define STAGEA(SB, J, TI)                                                     \
  __builtin_amdgcn_global_load_lds(                                           \
      (const __attribute__((address_space(1))) void*)(const void*)(           \
          srcA + (size_t)(TI) * ABRICK + (J) * 8192),                         \
      (__attribute__((address_space(3))) void*)(void*)(                       \
          lds + (SB) + dA + (J) * 8192),                                      \
      16, 0, 0)
#define STAGEB(SB, J, TI)                                                     \
  __builtin_amdgcn_global_load_lds(                                           \
      (const __attribute__((address_space(1))) void*)(const void*)(           \
          srcB + (size_t)(TI) * BBRICK + (J) * 8192),                         \
      (__attribute__((address_space(3))) void*)(void*)(                       \
          lds + (SB) + dB + (J) * 8192),                                      \
      16, 0, 0)

// Fragment read: two conflict-free ds_read_b128 (lane*16 stride) + combine.
#define LDA(OUT, M)                                                           \
  {                                                                           \
    const unsigned char* _b =                                                 \
        lds + rb + ((wr * 4 + (M)) << 11) + (lane << 4);                      \
    i32x4 _lo = *(const i32x4*)(_b);                                          \
    i32x4 _hi = *(const i32x4*)(_b + 1024);                                   \
    OUT = __builtin_shufflevector(_lo, _hi, 0, 1, 2, 3, 4, 5, 6, 7);          \
  }
#define LDB(OUT, N)                                                           \
  {                                                                           \
    const unsigned char* _b =                                                 \
        lds + rb + 32768 + ((wc * 4 + (N)) << 11) + (lane << 4);              \
    i32x4 _lo = *(const i32x4*)(_b);                                          \
    i32x4 _hi = *(const i32x4*)(_b + 1024);                                   \
    OUT = __builtin_shufflevector(_lo, _hi, 0, 1, 2, 3, 4, 5, 6, 7);          \
  }

#define MFMA(AF, BF, M, N)                                                    \
  acc[M][N] = __builtin_amdgcn_mfma_scale_f32_16x16x128_f8f6f4(               \
      AF, BF, acc[M][N], 0, 0, 0, 127, 0, 127)

__global__ __launch_bounds__(512, 1) void siglip_gemm(
    const unsigned char* __restrict__ A8,
    const unsigned char* __restrict__ B8,
    float* __restrict__ partials) {
  __shared__ unsigned char lds[3 * BUFSZ];  // 144 KB triple buffer
  __shared__ float wsum[8];

  const int tid = threadIdx.x;
  const int wave = tid >> 6;
  const int lane = tid & 63;
  const int wr = wave >> 1;  // 0..3 -> 64-row strip
  const int wc = wave & 1;   // 0..1 -> 64-col strip
  const int brow = blockIdx.y;
  const int bcol = blockIdx.x;

  f32x4 acc[4][4];
#pragma unroll
  for (int m = 0; m < 4; ++m)
#pragma unroll
    for (int n = 0; n < 4; ++n) acc[m][n] = f32x4{0.f, 0.f, 0.f, 0.f};

  const unsigned char* srcA =
      A8 + (size_t)brow * (NT * ABRICK) + wave * 1024 + (lane << 4);
  const unsigned char* srcB =
      B8 + (size_t)bcol * (NT * BBRICK) + wave * 1024 + (lane << 4);
  const int dA = wave * 1024;
  const int dB = 32768 + wave * 1024;

  // Prologue: tile0 -> buf0, tile1 -> buf1, drain tile0 only (vmcnt 6).
  STAGEA(0, 0, 0); STAGEA(0, 1, 0); STAGEA(0, 2, 0); STAGEA(0, 3, 0);
  STAGEB(0, 0, 0); STAGEB(0, 1, 0);
  STAGEA(BUFSZ, 0, 1); STAGEA(BUFSZ, 1, 1);
  STAGEA(BUFSZ, 2, 1); STAGEA(BUFSZ, 3, 1);
  STAGEB(BUFSZ, 0, 1); STAGEB(BUFSZ, 1, 1);
  asm volatile("s_waitcnt vmcnt(6)" ::: "memory");
  __builtin_amdgcn_s_barrier();
  __builtin_amdgcn_sched_barrier(0);

  int rb = 0;  // read buffer; stage buffer = rb + 2*BUFSZ (mod 3)
  for (int T = 0; T < NT; ++T) {
    int sb = rb + 2 * BUFSZ;
    if (sb >= 3 * BUFSZ) sb -= 3 * BUFSZ;

    // Fragment reads for this K-tile (16x ds_read_b128, conflict-free).
    // Plain loads: compiler interleaves MFMAs with counted lgkmcnt.
    i32x8 b0, b1, b2, b3, a0, a1, a2, a3;
    LDB(b0, 0); LDB(b1, 1); LDB(b2, 2); LDB(b3, 3);
    LDA(a0, 0); LDA(a1, 1); LDA(a2, 2); LDA(a3, 3);

    // Stage tile T+2 into the slot tile T-1 occupied (consumed before the
    // barrier that ended iter T-1). Per-wave vmcnt(6): own T+1 writes landed.
    if (T < NT - 2) {
      STAGEA(sb, 0, T + 2); STAGEA(sb, 1, T + 2);
      STAGEA(sb, 2, T + 2); STAGEA(sb, 3, T + 2);
      STAGEB(sb, 0, T + 2); STAGEB(sb, 1, T + 2);
      asm volatile("s_waitcnt vmcnt(6)" ::: "memory");
    } else if (T == NT - 2) {
      asm volatile("s_waitcnt vmcnt(0)" ::: "memory");
    }

    __builtin_amdgcn_s_setprio(1);
    MFMA(a0, b0, 0, 0); MFMA(a0, b1, 0, 1); MFMA(a0, b2, 0, 2); MFMA(a0, b3, 0, 3);
    MFMA(a1, b0, 1, 0); MFMA(a1, b1, 1, 1); MFMA(a1, b2, 1, 2); MFMA(a1, b3, 1, 3);
    MFMA(a2, b0, 2, 0); MFMA(a2, b1, 2, 1); MFMA(a2, b2, 2, 2); MFMA(a2, b3, 2, 3);
    MFMA(a3, b0, 3, 0); MFMA(a3, b1, 3, 1); MFMA(a3, b2, 3, 2); MFMA(a3, b3, 3, 3);
    __builtin_amdgcn_s_setprio(0);

    // One barrier per K-tile: publishes everyone's T+1 staging (vmcnt above)
    // and certifies tile T consumed. sched_barrier pins next-iter ds_reads
    // below it (they must not hoist above the barrier).
    __builtin_amdgcn_s_barrier();
    __builtin_amdgcn_sched_barrier(0);

    rb += BUFSZ;
    if (rb == 3 * BUFSZ) rb = 0;
  }

  // Epilogue. C/D 16x16 map: col = lane&15, row = (lane>>4)*4 + r.
  const int rbase = brow * BM + wr * 64 + (lane >> 4) * 4;
  const int cbase = bcol * BN + wc * 64 + (lane & 15);
  float lsum;
  if ((bcol >> 1) == brow)  // this 128-col strip overlaps the 256-row strip
    lsum = softplus_sum<true>(acc, rbase, cbase);
  else
    lsum = softplus_sum<false>(acc, rbase, cbase);

#pragma unroll
  for (int off = 32; off > 0; off >>= 1) lsum += __shfl_down(lsum, off);
  if (lane == 0) wsum[wave] = lsum;
  __syncthreads();
  if (tid == 0) {
    float s = 0.f;
#pragma unroll
    for (int w = 0; w < 8; ++w) s += wsum[w];
    partials[blockIdx.y * gridDim.x + blockIdx.x] = s;
  }
}

__global__ void reduce_kernel(const float* __restrict__ partials, int n,
                              float* __restrict__ out) {
  __shared__ float s[256];
  float v = 0.f;
  for (int i = threadIdx.x; i < n; i += 256) v += partials[i];
  s[threadIdx.x] = v;
  __syncthreads();
  for (int off = 128; off > 0; off >>= 1) {
    if ((int)threadIdx.x < off) s[threadIdx.x] += s[threadIdx.x + off];
    __syncthreads();
  }
  if (threadIdx.x == 0) out[0] = s[0] / (float)B_DIM;
}

extern "C" void kernel_launch(void* const* d_in, const int* in_sizes, int n_in,
                              void* d_out, int out_size, void* d_ws, size_t ws_size,
                              hipStream_t stream) {
  const float* emb1 = (const float*)d_in[0];
  const float* emb2 = (const float*)d_in[1];

  unsigned char* A8 = (unsigned char*)d_ws;                // 8 MB (bricked)
  unsigned char* B8 = A8 + (size_t)B_DIM * K_DIM;          // 8 MB (bricked)
  float* partials = (float*)(B8 + (size_t)B_DIM * K_DIM);  // 8 KB

  const float INV_T = 1.0f / 0.07f;
  const int nthreads = B_DIM * K_DIM / 16;  // 16 out bytes per thread
  cvt_fp8_brick<BM><<<nthreads / 256, 256, 0, stream>>>(emb1, A8, INV_T);
  cvt_fp8_brick<BN><<<nthreads / 256, 256, 0, stream>>>(emb2, B8, 1.0f);

  dim3 grid(B_DIM / BN, B_DIM / BM);  // 64 x 32
  siglip_gemm<<<grid, 512, 0, stream>>>(A8, B8, partials);

  const int nparts = (B_DIM / BM) * (B_DIM / BN);
  reduce_kernel<<<1, 256, 0, stream>>>(partials, nparts, (float*)d_out);
}

// Round 10
// 119.499 us; speedup vs baseline: 9.4223x; 1.0206x over previous
//
#include <hip/hip_runtime.h>

// SigLIP contrastive loss:
//   logits = emb1 @ emb2^T / 0.07           [B,B], B=8192, D=1024
//   loss = ( sum_i softplus(-l_ii) + sum_{i!=j} softplus(l_ij) ) / B
// R10: compile-time addressing. R8/R9 invariant VALUBusy ~44% = dominant
// pipe (1734 cyc/K-tile vs 1104 MFMA): runtime rb/sb/T+2 address arithmetic.
// Fully unroll the 8-K-tile loop so every LDS offset is a DS immediate and
// staging offsets are constants. Data/sync plane identical to R9 (passed).
// cvt kernels fused into one launch.

#define B_DIM 8192
#define K_DIM 1024
#define BM 256                 // tile rows (A panel)
#define BN 128                 // tile cols (B panel)
#define BKB 128                // K bytes per K-tile
#define NT (K_DIM / BKB)       // 8 K-tiles
#define ABRICK 32768           // 256 rows x 128 B
#define BBRICK 16384           // 128 rows x 128 B
#define BUFSZ 49152            // LDS buffer: A 32K + B 16K

typedef int i32x4 __attribute__((ext_vector_type(4)));
typedef int i32x8 __attribute__((ext_vector_type(8)));
typedef float f32x4 __attribute__((ext_vector_type(4)));

// f32 -> fp8 e4m3 brick permutation. One thread = 16 output bytes.
// Brick offset = fb*2048 + h*1024 + kch*256 + lr*16.
// Source: row = p*PANEL + fb*16 + lr, k byte = t*128 + kch*32 + h*16.
template <int PANEL>
__device__ __forceinline__ void brick_store(const float* __restrict__ in,
                                            unsigned char* __restrict__ out,
                                            float scale, int i) {
  constexpr int BRICK = PANEL * 128;
  const int o = i * 16;
  const int b = o / BRICK;
  const int p = b >> 3, t = b & 7;        // NT==8 bricks per panel strip
  const int w = o & (BRICK - 1);
  const int fb = w >> 11;
  const int h = (w >> 10) & 1;
  const int kch = (w >> 8) & 3;
  const int lr = (w >> 4) & 15;
  const int row = p * PANEL + fb * 16 + lr;
  const int kb = t * 128 + kch * 32 + h * 16;
  const float4* src = (const float4*)(in + (size_t)row * K_DIM + kb);
  float4 v0 = src[0], v1 = src[1], v2 = src[2], v3 = src[3];
  unsigned w0 = 0, w1 = 0, w2 = 0, w3 = 0;
  w0 = __builtin_amdgcn_cvt_pk_fp8_f32(v0.x * scale, v0.y * scale, w0, 0);
  w0 = __builtin_amdgcn_cvt_pk_fp8_f32(v0.z * scale, v0.w * scale, w0, 1);
  w1 = __builtin_amdgcn_cvt_pk_fp8_f32(v1.x * scale, v1.y * scale, w1, 0);
  w1 = __builtin_amdgcn_cvt_pk_fp8_f32(v1.z * scale, v1.w * scale, w1, 1);
  w2 = __builtin_amdgcn_cvt_pk_fp8_f32(v2.x * scale, v2.y * scale, w2, 0);
  w2 = __builtin_amdgcn_cvt_pk_fp8_f32(v2.z * scale, v2.w * scale, w2, 1);
  w3 = __builtin_amdgcn_cvt_pk_fp8_f32(v3.x * scale, v3.y * scale, w3, 0);
  w3 = __builtin_amdgcn_cvt_pk_fp8_f32(v3.z * scale, v3.w * scale, w3, 1);
  *(uint4*)(out + o) = make_uint4(w0, w1, w2, w3);
}

__global__ __launch_bounds__(256) void cvt_fused(
    const float* __restrict__ e1, const float* __restrict__ e2,
    unsigned char* __restrict__ A8, unsigned char* __restrict__ B8,
    int nbA, float scaleA) {
  const int blk = blockIdx.x;
  if (blk < nbA)
    brick_store<BM>(e1, A8, scaleA, blk * 256 + threadIdx.x);
  else
    brick_store<BN>(e2, B8, 1.0f, (blk - nbA) * 256 + threadIdx.x);
}

// Cheap softplus accumulate: softplus(x) = max(x,0) + log(1+exp(-|x|)).
template <bool DIAG>
__device__ __forceinline__ float softplus_sum(const f32x4 (&acc)[4][4],
                                              int rbase, int cbase) {
  float lin = 0.f, cor = 0.f;
#pragma unroll
  for (int m = 0; m < 4; ++m) {
#pragma unroll
    for (int n = 0; n < 4; ++n) {
#pragma unroll
      for (int r = 0; r < 4; ++r) {
        float x = acc[m][n][r];
        if (DIAG) {
          int row = rbase + m * 16 + r;
          int col = cbase + n * 16;
          if (row == col) x = -x;  // diagonal: softplus(-l_ii)
        }
        lin += fmaxf(x, 0.f);
        cor += __logf(1.f + __expf(-fabsf(x)));
      }
    }
  }
  return lin + cor;
}

// Staging: 48KB per K-tile as 48 linear 1024B slices (A 32, B 16); wave w
// takes slice j*8+w. Brick source and LDS dest are both linear.
#define STAGEA(SB, J, TI)                                                     \
  __builtin_amdgcn_global_load_lds(                                           \
      (const __attribute__((address_space(1))) void*)(const void*)(           \
          srcA + (TI) * ABRICK + (J) * 8192),                                 \
      (__attribute__((address_space(3))) void*)(void*)(                       \
          lds + (SB) + dA + (J) * 8192),                                      \
      16, 0, 0)
#define STAGEB(SB, J, TI)                                                     \
  __builtin_amdgcn_global_load_lds(                                           \
      (const __attribute__((address_space(1))) void*)(const void*)(           \
          srcB + (TI) * BBRICK + (J) * 8192),                                 \
      (__attribute__((address_space(3))) void*)(void*)(                       \
          lds + (SB) + dB + (J) * 8192),                                      \
      16, 0, 0)

// Fragment read: two conflict-free ds_read_b128 (lane*16 stride) + combine.
// RB/frag indices are compile-time after unroll -> DS offset immediates.
#define LDA(OUT, RB, M)                                                       \
  {                                                                           \
    const unsigned char* _b =                                                 \
        ldsL + ((RB) + ((wr * 4 + (M)) << 11));                               \
    i32x4 _lo = *(const i32x4*)(_b);                                          \
    i32x4 _hi = *(const i32x4*)(_b + 1024);                                   \
    OUT = __builtin_shufflevector(_lo, _hi, 0, 1, 2, 3, 4, 5, 6, 7);          \
  }
#define LDB(OUT, RB, N)                                                       \
  {                                                                           \
    const unsigned char* _b =                                                 \
        ldsL + ((RB) + 32768 + ((wc * 4 + (N)) << 11));                       \
    i32x4 _lo = *(const i32x4*)(_b);                                          \
    i32x4 _hi = *(const i32x4*)(_b + 1024);                                   \
    OUT = __builtin_shufflevector(_lo, _hi, 0, 1, 2, 3, 4, 5, 6, 7);          \
  }

#define MFMA(AF, BF, M, N)                                                    \
  acc[M][N] = __builtin_amdgcn_mfma_scale_f32_16x16x128_f8f6f4(               \
      AF, BF, acc[M][N], 0, 0, 0, 127, 0, 127)

__global__ __launch_bounds__(512, 1) void siglip_gemm(
    const unsigned char* __restrict__ A8,
    const unsigned char* __restrict__ B8,
    float* __restrict__ partials) {
  __shared__ unsigned char lds[3 * BUFSZ];  // 144 KB triple buffer
  __shared__ float wsum[8];

  const int tid = threadIdx.x;
  const int wave = tid >> 6;
  const int lane = tid & 63;
  const int wr = wave >> 1;  // 0..3 -> 64-row strip
  const int wc = wave & 1;   // 0..1 -> 64-col strip
  const int brow = blockIdx.y;
  const int bcol = blockIdx.x;

  f32x4 acc[4][4];
#pragma unroll
  for (int m = 0; m < 4; ++m)
#pragma unroll
    for (int n = 0; n < 4; ++n) acc[m][n] = f32x4{0.f, 0.f, 0.f, 0.f};

  const unsigned char* srcA =
      A8 + (size_t)brow * (NT * ABRICK) + wave * 1024 + (lane << 4);
  const unsigned char* srcB =
      B8 + (size_t)bcol * (NT * BBRICK) + wave * 1024 + (lane << 4);
  const int dA = wave * 1024;
  const int dB = 32768 + wave * 1024;
  const unsigned char* ldsL = lds + (lane << 4);  // per-lane read base

  // Prologue: tile0 -> buf0, tile1 -> buf1, drain tile0 only (vmcnt 6).
  STAGEA(0, 0, 0); STAGEA(0, 1, 0); STAGEA(0, 2, 0); STAGEA(0, 3, 0);
  STAGEB(0, 0, 0); STAGEB(0, 1, 0);
  STAGEA(BUFSZ, 0, 1); STAGEA(BUFSZ, 1, 1);
  STAGEA(BUFSZ, 2, 1); STAGEA(BUFSZ, 3, 1);
  STAGEB(BUFSZ, 0, 1); STAGEB(BUFSZ, 1, 1);
  asm volatile("s_waitcnt vmcnt(6)" ::: "memory");
  __builtin_amdgcn_s_barrier();
  __builtin_amdgcn_sched_barrier(0);

#pragma unroll
  for (int T = 0; T < NT; ++T) {
    const int rb = (T % 3) * BUFSZ;        // compile-time after unroll
    const int sb = ((T + 2) % 3) * BUFSZ;  // stage slot (held tile T-1)

    // Fragment reads for this K-tile (16x ds_read_b128, conflict-free,
    // immediate offsets). Compiler interleaves MFMAs via counted lgkmcnt.
    i32x8 b0, b1, b2, b3, a0, a1, a2, a3;
    LDB(b0, rb, 0); LDB(b1, rb, 1); LDB(b2, rb, 2); LDB(b3, rb, 3);
    LDA(a0, rb, 0); LDA(a1, rb, 1); LDA(a2, rb, 2); LDA(a3, rb, 3);

    // Stage tile T+2 (constant offsets). Per-wave vmcnt(6): own T+1 landed.
    if (T < NT - 2) {
      STAGEA(sb, 0, T + 2); STAGEA(sb, 1, T + 2);
      STAGEA(sb, 2, T + 2); STAGEA(sb, 3, T + 2);
      STAGEB(sb, 0, T + 2); STAGEB(sb, 1, T + 2);
      asm volatile("s_waitcnt vmcnt(6)" ::: "memory");
    } else if (T == NT - 2) {
      asm volatile("s_waitcnt vmcnt(0)" ::: "memory");
    }

    __builtin_amdgcn_s_setprio(1);
    MFMA(a0, b0, 0, 0); MFMA(a0, b1, 0, 1); MFMA(a0, b2, 0, 2); MFMA(a0, b3, 0, 3);
    MFMA(a1, b0, 1, 0); MFMA(a1, b1, 1, 1); MFMA(a1, b2, 1, 2); MFMA(a1, b3, 1, 3);
    MFMA(a2, b0, 2, 0); MFMA(a2, b1, 2, 1); MFMA(a2, b2, 2, 2); MFMA(a2, b3, 2, 3);
    MFMA(a3, b0, 3, 0); MFMA(a3, b1, 3, 1); MFMA(a3, b2, 3, 2); MFMA(a3, b3, 3, 3);
    __builtin_amdgcn_s_setprio(0);

    // One barrier per K-tile: publishes everyone's T+1 staging (vmcnt above)
    // and certifies tile T consumed. sched_barrier pins next-tile ds_reads
    // below it.
    __builtin_amdgcn_s_barrier();
    __builtin_amdgcn_sched_barrier(0);
  }

  // Epilogue. C/D 16x16 map: col = lane&15, row = (lane>>4)*4 + r.
  const int rbase = brow * BM + wr * 64 + (lane >> 4) * 4;
  const int cbase = bcol * BN + wc * 64 + (lane & 15);
  float lsum;
  if ((bcol >> 1) == brow)  // this 128-col strip overlaps the 256-row strip
    lsum = softplus_sum<true>(acc, rbase, cbase);
  else
    lsum = softplus_sum<false>(acc, rbase, cbase);

#pragma unroll
  for (int off = 32; off > 0; off >>= 1) lsum += __shfl_down(lsum, off);
  if (lane == 0) wsum[wave] = lsum;
  __syncthreads();
  if (tid == 0) {
    float s = 0.f;
#pragma unroll
    for (int w = 0; w < 8; ++w) s += wsum[w];
    partials[blockIdx.y * gridDim.x + blockIdx.x] = s;
  }
}

__global__ void reduce_kernel(const float* __restrict__ partials, int n,
                              float* __restrict__ out) {
  __shared__ float s[256];
  float v = 0.f;
  for (int i = threadIdx.x; i < n; i += 256) v += partials[i];
  s[threadIdx.x] = v;
  __syncthreads();
  for (int off = 128; off > 0; off >>= 1) {
    if ((int)threadIdx.x < off) s[threadIdx.x] += s[threadIdx.x + off];
    __syncthreads();
  }
  if (threadIdx.x == 0) out[0] = s[0] / (float)B_DIM;
}

extern "C" void kernel_launch(void* const* d_in, const int* in_sizes, int n_in,
                              void* d_out, int out_size, void* d_ws, size_t ws_size,
                              hipStream_t stream) {
  const float* emb1 = (const float*)d_in[0];
  const float* emb2 = (const float*)d_in[1];

  unsigned char* A8 = (unsigned char*)d_ws;                // 8 MB (bricked)
  unsigned char* B8 = A8 + (size_t)B_DIM * K_DIM;          // 8 MB (bricked)
  float* partials = (float*)(B8 + (size_t)B_DIM * K_DIM);  // 8 KB

  const float INV_T = 1.0f / 0.07f;
  const int nbA = (B_DIM * K_DIM / 16) / 256;  // 2048 blocks per operand
  cvt_fused<<<2 * nbA, 256, 0, stream>>>(emb1, emb2, A8, B8, nbA, INV_T);

  dim3 grid(B_DIM / BN, B_DIM / BM);  // 64 x 32
  siglip_gemm<<<grid, 512, 0, stream>>>(A8, B8, partials);

  const int nparts = (B_DIM / BM) * (B_DIM / BN);
  reduce_kernel<<<1, 256, 0, stream>>>(partials, nparts, (float*)d_out);
}

// Round 11
// 113.578 us; speedup vs baseline: 9.9135x; 1.0521x over previous
//
#include <hip/hip_runtime.h>

// SigLIP contrastive loss:
//   logits = emb1 @ emb2^T / 0.07           [B,B], B=8192, D=1024
//   loss = ( sum_i softplus(-l_ii) + sum_{i!=j} softplus(l_ij) ) / B
// R11: cross-block TLP. R8-R10 plateau = phase-lockstep (all waves
// barrier-synced -> LDS idle during MFMA, MFMA idle during reads; no pipe
// >44%). 128x128 tile, 4 waves, double-buffered 64 KB LDS -> 2 independent
// blocks/CU whose barriers decorrelate, filling both pipes (m114 mechanism).
// Data plane: fp8 bricks PANEL=128 (both operands), conflict-free lane*16
// frag reads, stage-early + vmcnt(0)-late, 1 barrier/K-tile.

#define B_DIM 8192
#define K_DIM 1024
#define BT 128                 // tile rows == cols
#define BKB 128                // K bytes per K-tile
#define NT (K_DIM / BKB)       // 8 K-tiles
#define BRICK 16384            // one (128-row panel, K-tile) brick
#define PANEL_BYTES (NT * BRICK)
#define BUFSZ 32768            // LDS buffer: A 16K + B 16K

typedef int i32x4 __attribute__((ext_vector_type(4)));
typedef int i32x8 __attribute__((ext_vector_type(8)));
typedef float f32x4 __attribute__((ext_vector_type(4)));

// f32 -> fp8 e4m3 brick permutation (PANEL=128). One thread = 16 out bytes.
// Brick offset = fb*2048 + h*1024 + kch*256 + lr*16.
// Source: row = p*128 + fb*16 + lr, k byte = t*128 + kch*32 + h*16.
__device__ __forceinline__ void brick_store(const float* __restrict__ in,
                                            unsigned char* __restrict__ out,
                                            float scale, int i) {
  const int o = i * 16;
  const int b = o >> 14;                  // brick index
  const int p = b >> 3, t = b & 7;        // panel, K-tile
  const int w = o & (BRICK - 1);
  const int fb = w >> 11;
  const int h = (w >> 10) & 1;
  const int kch = (w >> 8) & 3;
  const int lr = (w >> 4) & 15;
  const int row = p * 128 + fb * 16 + lr;
  const int kb = t * 128 + kch * 32 + h * 16;
  const float4* src = (const float4*)(in + (size_t)row * K_DIM + kb);
  float4 v0 = src[0], v1 = src[1], v2 = src[2], v3 = src[3];
  unsigned w0 = 0, w1 = 0, w2 = 0, w3 = 0;
  w0 = __builtin_amdgcn_cvt_pk_fp8_f32(v0.x * scale, v0.y * scale, w0, 0);
  w0 = __builtin_amdgcn_cvt_pk_fp8_f32(v0.z * scale, v0.w * scale, w0, 1);
  w1 = __builtin_amdgcn_cvt_pk_fp8_f32(v1.x * scale, v1.y * scale, w1, 0);
  w1 = __builtin_amdgcn_cvt_pk_fp8_f32(v1.z * scale, v1.w * scale, w1, 1);
  w2 = __builtin_amdgcn_cvt_pk_fp8_f32(v2.x * scale, v2.y * scale, w2, 0);
  w2 = __builtin_amdgcn_cvt_pk_fp8_f32(v2.z * scale, v2.w * scale, w2, 1);
  w3 = __builtin_amdgcn_cvt_pk_fp8_f32(v3.x * scale, v3.y * scale, w3, 0);
  w3 = __builtin_amdgcn_cvt_pk_fp8_f32(v3.z * scale, v3.w * scale, w3, 1);
  *(uint4*)(out + o) = make_uint4(w0, w1, w2, w3);
}

__global__ __launch_bounds__(256) void cvt_fused(
    const float* __restrict__ e1, const float* __restrict__ e2,
    unsigned char* __restrict__ A8, unsigned char* __restrict__ B8,
    int nbA, float scaleA) {
  const int blk = blockIdx.x;
  if (blk < nbA)
    brick_store(e1, A8, scaleA, blk * 256 + threadIdx.x);
  else
    brick_store(e2, B8, 1.0f, (blk - nbA) * 256 + threadIdx.x);
}

// Cheap softplus accumulate: softplus(x) = max(x,0) + log(1+exp(-|x|)).
template <bool DIAG>
__device__ __forceinline__ float softplus_sum(const f32x4 (&acc)[4][4],
                                              int rbase, int cbase) {
  float lin = 0.f, cor = 0.f;
#pragma unroll
  for (int m = 0; m < 4; ++m) {
#pragma unroll
    for (int n = 0; n < 4; ++n) {
#pragma unroll
      for (int r = 0; r < 4; ++r) {
        float x = acc[m][n][r];
        if (DIAG) {
          int row = rbase + m * 16 + r;
          int col = cbase + n * 16;
          if (row == col) x = -x;  // diagonal: softplus(-l_ii)
        }
        lin += fmaxf(x, 0.f);
        cor += __logf(1.f + __expf(-fabsf(x)));
      }
    }
  }
  return lin + cor;
}

// Staging: 32 KB/K-tile as 32 linear 1024B slices (A 16, B 16); wave w takes
// slices w*4..w*4+3 of each operand. srcA/srcB include wave*4096 + lane*16.
#define STAGEA(SB, Q, TI)                                                     \
  __builtin_amdgcn_global_load_lds(                                           \
      (const __attribute__((address_space(1))) void*)(const void*)(           \
          srcA + (TI) * BRICK + (Q) * 1024),                                  \
      (__attribute__((address_space(3))) void*)(void*)(                       \
          lds + (SB) + dA + (Q) * 1024),                                      \
      16, 0, 0)
#define STAGEB(SB, Q, TI)                                                     \
  __builtin_amdgcn_global_load_lds(                                           \
      (const __attribute__((address_space(1))) void*)(const void*)(           \
          srcB + (TI) * BRICK + (Q) * 1024),                                  \
      (__attribute__((address_space(3))) void*)(void*)(                       \
          lds + (SB) + dB + (Q) * 1024),                                      \
      16, 0, 0)

// Fragment read: two conflict-free ds_read_b128 (lane*16 stride) + combine.
#define LDA(OUT, RB, M)                                                       \
  {                                                                           \
    const unsigned char* _b = ldsL + ((RB) + ((wr * 4 + (M)) << 11));         \
    i32x4 _lo = *(const i32x4*)(_b);                                          \
    i32x4 _hi = *(const i32x4*)(_b + 1024);                                   \
    OUT = __builtin_shufflevector(_lo, _hi, 0, 1, 2, 3, 4, 5, 6, 7);          \
  }
#define LDB(OUT, RB, N)                                                       \
  {                                                                           \
    const unsigned char* _b = ldsL + ((RB) + 16384 + ((wc * 4 + (N)) << 11)); \
    i32x4 _lo = *(const i32x4*)(_b);                                          \
    i32x4 _hi = *(const i32x4*)(_b + 1024);                                   \
    OUT = __builtin_shufflevector(_lo, _hi, 0, 1, 2, 3, 4, 5, 6, 7);          \
  }

#define MFMA(AF, BF, M, N)                                                    \
  acc[M][N] = __builtin_amdgcn_mfma_scale_f32_16x16x128_f8f6f4(               \
      AF, BF, acc[M][N], 0, 0, 0, 127, 0, 127)

__global__ __launch_bounds__(256, 2) void siglip_gemm(
    const unsigned char* __restrict__ A8,
    const unsigned char* __restrict__ B8,
    float* __restrict__ partials) {
  __shared__ unsigned char lds[2 * BUFSZ];  // 64 KB double buffer
  __shared__ float wsum[4];

  const int tid = threadIdx.x;
  const int wave = tid >> 6;
  const int lane = tid & 63;
  const int wr = wave >> 1;  // 0..1 -> 64-row strip
  const int wc = wave & 1;   // 0..1 -> 64-col strip
  const int brow = blockIdx.y;
  const int bcol = blockIdx.x;

  f32x4 acc[4][4];
#pragma unroll
  for (int m = 0; m < 4; ++m)
#pragma unroll
    for (int n = 0; n < 4; ++n) acc[m][n] = f32x4{0.f, 0.f, 0.f, 0.f};

  const unsigned char* srcA =
      A8 + (size_t)brow * PANEL_BYTES + wave * 4096 + (lane << 4);
  const unsigned char* srcB =
      B8 + (size_t)bcol * PANEL_BYTES + wave * 4096 + (lane << 4);
  const int dA = wave * 4096;
  const int dB = 16384 + wave * 4096;
  const unsigned char* ldsL = lds + (lane << 4);  // per-lane read base

  // Prologue: stage tile 0 into buf 0, full drain, publish.
  STAGEA(0, 0, 0); STAGEA(0, 1, 0); STAGEA(0, 2, 0); STAGEA(0, 3, 0);
  STAGEB(0, 0, 0); STAGEB(0, 1, 0); STAGEB(0, 2, 0); STAGEB(0, 3, 0);
  asm volatile("s_waitcnt vmcnt(0)" ::: "memory");
  __builtin_amdgcn_s_barrier();
  __builtin_amdgcn_sched_barrier(0);

#pragma unroll
  for (int T = 0; T < NT; ++T) {
    const int rb = (T & 1) * BUFSZ;   // read buffer (tile T)
    const int sb = rb ^ BUFSZ;        // stage buffer (tile T+1; held T-1)

    // Fragment reads for tile T (16x ds_read_b128, conflict-free, imm offs).
    i32x8 b0, b1, b2, b3, a0, a1, a2, a3;
    LDB(b0, rb, 0); LDB(b1, rb, 1); LDB(b2, rb, 2); LDB(b3, rb, 3);
    LDA(a0, rb, 0); LDA(a1, rb, 1); LDA(a2, rb, 2); LDA(a3, rb, 3);

    // Stage tile T+1 early; latency hides under the MFMA cluster below.
    if (T < NT - 1) {
      STAGEA(sb, 0, T + 1); STAGEA(sb, 1, T + 1);
      STAGEA(sb, 2, T + 1); STAGEA(sb, 3, T + 1);
      STAGEB(sb, 0, T + 1); STAGEB(sb, 1, T + 1);
      STAGEB(sb, 2, T + 1); STAGEB(sb, 3, T + 1);
    }
    __builtin_amdgcn_sched_barrier(0);  // pin stage issue before MFMAs

    __builtin_amdgcn_s_setprio(1);
    MFMA(a0, b0, 0, 0); MFMA(a0, b1, 0, 1); MFMA(a0, b2, 0, 2); MFMA(a0, b3, 0, 3);
    MFMA(a1, b0, 1, 0); MFMA(a1, b1, 1, 1); MFMA(a1, b2, 1, 2); MFMA(a1, b3, 1, 3);
    MFMA(a2, b0, 2, 0); MFMA(a2, b1, 2, 1); MFMA(a2, b2, 2, 2); MFMA(a2, b3, 2, 3);
    MFMA(a3, b0, 3, 0); MFMA(a3, b1, 3, 1); MFMA(a3, b2, 3, 2); MFMA(a3, b3, 3, 3);
    __builtin_amdgcn_s_setprio(0);

    if (T < NT - 1) {
      // Own staging of T+1 landed (issued ~16 MFMAs ago -> latency hidden);
      // barrier publishes all waves' staging and certifies tile T consumed.
      asm volatile("s_waitcnt vmcnt(0)" ::: "memory");
      __builtin_amdgcn_s_barrier();
      __builtin_amdgcn_sched_barrier(0);
    }
  }

  // Epilogue. C/D 16x16 map: col = lane&15, row = (lane>>4)*4 + r.
  const int rbase = brow * BT + wr * 64 + (lane >> 4) * 4;
  const int cbase = bcol * BT + wc * 64 + (lane & 15);
  float lsum;
  if (brow == bcol)
    lsum = softplus_sum<true>(acc, rbase, cbase);
  else
    lsum = softplus_sum<false>(acc, rbase, cbase);

#pragma unroll
  for (int off = 32; off > 0; off >>= 1) lsum += __shfl_down(lsum, off);
  __syncthreads();  // all MFMA/LDS work done; reuse lds area not needed
  if (lane == 0) wsum[wave] = lsum;
  __syncthreads();
  if (tid == 0)
    partials[blockIdx.y * gridDim.x + blockIdx.x] =
        wsum[0] + wsum[1] + wsum[2] + wsum[3];
}

__global__ void reduce_kernel(const float* __restrict__ partials, int n,
                              float* __restrict__ out) {
  __shared__ float s[256];
  float v = 0.f;
  for (int i = threadIdx.x; i < n; i += 256) v += partials[i];
  s[threadIdx.x] = v;
  __syncthreads();
  for (int off = 128; off > 0; off >>= 1) {
    if ((int)threadIdx.x < off) s[threadIdx.x] += s[threadIdx.x + off];
    __syncthreads();
  }
  if (threadIdx.x == 0) out[0] = s[0] / (float)B_DIM;
}

extern "C" void kernel_launch(void* const* d_in, const int* in_sizes, int n_in,
                              void* d_out, int out_size, void* d_ws, size_t ws_size,
                              hipStream_t stream) {
  const float* emb1 = (const float*)d_in[0];
  const float* emb2 = (const float*)d_in[1];

  unsigned char* A8 = (unsigned char*)d_ws;                // 8 MB (bricked)
  unsigned char* B8 = A8 + (size_t)B_DIM * K_DIM;          // 8 MB (bricked)
  float* partials = (float*)(B8 + (size_t)B_DIM * K_DIM);  // 16 KB

  const float INV_T = 1.0f / 0.07f;
  const int nbA = (B_DIM * K_DIM / 16) / 256;  // 2048 blocks per operand
  cvt_fused<<<2 * nbA, 256, 0, stream>>>(emb1, emb2, A8, B8, nbA, INV_T);

  dim3 grid(B_DIM / BT, B_DIM / BT);  // 64 x 64
  siglip_gemm<<<grid, 256, 0, stream>>>(A8, B8, partials);

  const int nparts = (B_DIM / BT) * (B_DIM / BT);
  reduce_kernel<<<1, 256, 0, stream>>>(partials, nparts, (float*)d_out);
}